// Round 9
// baseline (438.558 us; speedup 1.0000x reference)
//
#include <hip/hip_runtime.h>

// AttentionActorCritic fused forward, MI355X (gfx950).
// Round 9: attribution split. k_enc = phase1+attention+phaseD -> enc[B,144,32]
// bf16 in d_ws; k_trunk = out_gemm+st_emb+d1+d2+heads (32 samples/block,
// hoisted A-frags). Fallback to r8 mono kernel if ws_size too small.

typedef __bf16 bhalf;
typedef __bf16 bhalf4 __attribute__((ext_vector_type(4)));
typedef __bf16 bhalf8 __attribute__((ext_vector_type(8)));
typedef float f32x4 __attribute__((ext_vector_type(4)));
typedef float f32x2 __attribute__((ext_vector_type(2)));

#define DEV static __device__ __forceinline__

DEV f32x4 mfma16(bhalf8 a, bhalf8 b, f32x4 c) {
  return __builtin_amdgcn_mfma_f32_16x16x32_bf16(a, b, c, 0, 0, 0);
}

// ---------------- pointer bundle ----------------
struct Ptrs {
  const float* state;
  const float *p_g1, *p_b1, *p_f1b, *p_f2b, *p_g2, *p_b2, *p_out_b;
  const float *s_g1, *s_b1, *s_f1b, *s_f2b, *s_g2, *s_b2, *s_out_b;
  const float *d1_b, *d2_b, *pi_w, *pi_b, *v_w, *v_b;
  const bhalf *A_qp, *A_xp, *w_o, *w_f1, *w_f2, *w_out;
  const bhalf *A_qs, *A_xs, *w_o2, *w_f12, *w_f22, *w_out2;
  const bhalf *A_e, *w_d1, *w_d2;
  bhalf* enc;
  float* out;
};

// ---------------- prep kernels (unchanged) ----------------
struct PrepArgs {
  const float* src[10];
  int len[10];
  int dstOff[10];
  bhalf* dst;
};

__global__ void prep_convert(PrepArgs a) {
  int idx = blockIdx.x * blockDim.x + threadIdx.x;
  int off = 0;
#pragma unroll
  for (int i = 0; i < 10; ++i) {
    int n = a.len[i];
    if (idx >= off && idx < off + n) a.dst[a.dstOff[i] + idx - off] = (bhalf)a.src[i][idx - off];
    off += n;
  }
}

struct EffArgs {
  const float *p_qkv_w, *p_in_w, *p_in_b, *p_qkv_b, *p_o_b;
  const float *s_qkv_w, *s_in_w, *s_in_b, *s_qkv_b, *s_o_b;
  const float *e_w, *e_b;
  bhalf* dst;
};

__global__ void prep_eff(EffArgs a) {
  int tid = threadIdx.x;
  if (tid < 96) {
    const float* wq = a.p_qkv_w + tid * 32;
    float w0 = 0.f, w1 = 0.f, be = 0.f;
    for (int e = 0; e < 32; ++e) {
      w0 += wq[e] * a.p_in_w[e * 2];
      w1 += wq[e] * a.p_in_w[e * 2 + 1];
      be += wq[e] * a.p_in_b[e];
    }
    be += a.p_qkv_b[tid];
    bhalf* d = a.dst + tid * 32;
    for (int k = 0; k < 32; ++k) d[k] = (bhalf)0.f;
    d[0] = (bhalf)w0; d[1] = (bhalf)w1; d[2] = (bhalf)be;
  } else if (tid < 192) {
    int o = tid - 96;
    const float* wq = a.s_qkv_w + o * 32;
    float wf[4] = {0.f, 0.f, 0.f, 0.f}, be = 0.f;
    for (int e = 0; e < 32; ++e) {
      for (int f = 0; f < 4; ++f) wf[f] += wq[e] * a.s_in_w[e * 4 + f];
      be += wq[e] * a.s_in_b[e];
    }
    be += a.s_qkv_b[o];
    bhalf* d = a.dst + 35840 + o * 32;
    for (int k = 0; k < 32; ++k) d[k] = (bhalf)0.f;
    for (int f = 0; f < 4; ++f) d[f] = (bhalf)wf[f];
    d[4] = (bhalf)be;
  } else if (tid < 224) {
    int e = tid - 192;
    bhalf* d = a.dst + 3072 + e * 32;
    for (int k = 0; k < 32; ++k) d[k] = (bhalf)0.f;
    d[0] = (bhalf)a.p_in_w[e * 2];
    d[1] = (bhalf)a.p_in_w[e * 2 + 1];
    d[2] = (bhalf)(a.p_in_b[e] + a.p_o_b[e]);
  } else if (tid < 256) {
    int e = tid - 224;
    bhalf* d = a.dst + 38912 + e * 32;
    for (int k = 0; k < 32; ++k) d[k] = (bhalf)0.f;
    for (int f = 0; f < 4; ++f) d[f] = (bhalf)a.s_in_w[e * 4 + f];
    d[4] = (bhalf)(a.s_in_b[e] + a.s_o_b[e]);
  } else if (tid < 384) {
    int o = tid - 256;
    bhalf* d = a.dst + 51200 + o * 32;
    for (int k = 0; k < 32; ++k) d[k] = (bhalf)0.f;
    for (int k = 0; k < 8; ++k) d[k] = (bhalf)a.e_w[o * 8 + k];
    d[8] = (bhalf)a.e_b[o];
  }
}

// ---------------- attention (reg output) ----------------
template <int T>
DEV bhalf8 attn_head(const bhalf* qkv, int rowbase, int a, int s, int h) {
  const bhalf* base = &qkv[(rowbase + s) * 100 + h * 8];
  const int rstep = 16 * 100;
  bhalf8 kf[T];
#pragma unroll
  for (int b = 0; b < T; ++b) kf[b] = *(const bhalf8*)(base + b * rstep + 32);
  bhalf8 qv = *(const bhalf8*)(base + a * rstep);
  float q[8];
#pragma unroll
  for (int i = 0; i < 8; ++i) q[i] = (float)qv[i];
  float sc[T];
  float mx = -1e30f;
#pragma unroll
  for (int b = 0; b < T; ++b) {
    float d = 0.f;
#pragma unroll
    for (int i = 0; i < 8; ++i) d += q[i] * (float)kf[b][i];
    d *= 0.35355339059327378f;
    sc[b] = d;
    mx = fmaxf(mx, d);
  }
  bhalf8 vf[T];
#pragma unroll
  for (int b = 0; b < T; ++b) vf[b] = *(const bhalf8*)(base + b * rstep + 64);
  float sum = 0.f;
#pragma unroll
  for (int b = 0; b < T; ++b) { sc[b] = __expf(sc[b] - mx); sum += sc[b]; }
  float inv = 1.f / sum;
  float o[8] = {0.f, 0.f, 0.f, 0.f, 0.f, 0.f, 0.f, 0.f};
#pragma unroll
  for (int b = 0; b < T; ++b) {
    float w = sc[b] * inv;
#pragma unroll
    for (int i = 0; i < 8; ++i) o[i] += w * (float)vf[b][i];
  }
  bhalf8 ov;
#pragma unroll
  for (int i = 0; i < 8; ++i) ov[i] = (bhalf)o[i];
  return ov;
}

// ---------------- phase-D (wave-local) ----------------
DEV void phaseD(bhalf8 ov, int row, int l15, int lq, bhalf* s_x,
                const bhalf* wo, const bhalf* wf1, const bhalf* wf2,
                const float* g1, const float* b1, const float* f1b,
                const float* f2b, const float* g2, const float* b2) {
  const int boff = row * 40;
  bhalf4 x0 = *(const bhalf4*)&s_x[boff + lq * 4];
  bhalf4 x1 = *(const bhalf4*)&s_x[boff + 16 + lq * 4];
  f32x4 c0, c1;
#pragma unroll
  for (int j = 0; j < 4; ++j) { c0[j] = (float)x0[j]; c1[j] = (float)x1[j]; }
  c0 = mfma16(*(const bhalf8*)&wo[l15 * 32 + lq * 8], ov, c0);
  c1 = mfma16(*(const bhalf8*)&wo[(16 + l15) * 32 + lq * 8], ov, c1);
  float sum = 0.f, ss = 0.f;
#pragma unroll
  for (int j = 0; j < 4; ++j) { sum += c0[j] + c1[j]; ss += c0[j] * c0[j] + c1[j] * c1[j]; }
  sum += __shfl_xor(sum, 16); sum += __shfl_xor(sum, 32);
  ss += __shfl_xor(ss, 16); ss += __shfl_xor(ss, 32);
  float mu = sum * 0.03125f;
  float rs = rsqrtf(ss * 0.03125f - mu * mu + 1e-5f);
  f32x4 gg0 = *(const f32x4*)&g1[lq * 4], gg1 = *(const f32x4*)&g1[16 + lq * 4];
  f32x4 hb0 = *(const f32x4*)&b1[lq * 4], hb1 = *(const f32x4*)&b1[16 + lq * 4];
  float xn[8];
#pragma unroll
  for (int j = 0; j < 4; ++j) {
    xn[j] = (c0[j] - mu) * rs * gg0[j] + hb0[j];
    xn[4 + j] = (c1[j] - mu) * rs * gg1[j] + hb1[j];
  }
  bhalf4 p0, p1;
#pragma unroll
  for (int j = 0; j < 4; ++j) { p0[j] = (bhalf)xn[j]; p1[j] = (bhalf)xn[4 + j]; }
  *(bhalf4*)&s_x[boff + lq * 4] = p0;
  *(bhalf4*)&s_x[boff + 16 + lq * 4] = p1;
  bhalf8 bfr = *(const bhalf8*)&s_x[boff + lq * 8];
  c0 = f32x4{0.f, 0.f, 0.f, 0.f};
  c1 = f32x4{0.f, 0.f, 0.f, 0.f};
  c0 = mfma16(*(const bhalf8*)&wf1[l15 * 32 + lq * 8], bfr, c0);
  c1 = mfma16(*(const bhalf8*)&wf1[(16 + l15) * 32 + lq * 8], bfr, c1);
  f32x4 fb0 = *(const f32x4*)&f1b[lq * 4], fb1 = *(const f32x4*)&f1b[16 + lq * 4];
#pragma unroll
  for (int j = 0; j < 4; ++j) {
    p0[j] = (bhalf)fmaxf(c0[j] + fb0[j], 0.f);
    p1[j] = (bhalf)fmaxf(c1[j] + fb1[j], 0.f);
  }
  *(bhalf4*)&s_x[boff + lq * 4] = p0;
  *(bhalf4*)&s_x[boff + 16 + lq * 4] = p1;
  bfr = *(const bhalf8*)&s_x[boff + lq * 8];
  f32x4 f20 = *(const f32x4*)&f2b[lq * 4], f21 = *(const f32x4*)&f2b[16 + lq * 4];
#pragma unroll
  for (int j = 0; j < 4; ++j) { c0[j] = xn[j] + f20[j]; c1[j] = xn[4 + j] + f21[j]; }
  c0 = mfma16(*(const bhalf8*)&wf2[l15 * 32 + lq * 8], bfr, c0);
  c1 = mfma16(*(const bhalf8*)&wf2[(16 + l15) * 32 + lq * 8], bfr, c1);
  sum = 0.f; ss = 0.f;
#pragma unroll
  for (int j = 0; j < 4; ++j) { sum += c0[j] + c1[j]; ss += c0[j] * c0[j] + c1[j] * c1[j]; }
  sum += __shfl_xor(sum, 16); sum += __shfl_xor(sum, 32);
  ss += __shfl_xor(ss, 16); ss += __shfl_xor(ss, 32);
  mu = sum * 0.03125f;
  rs = rsqrtf(ss * 0.03125f - mu * mu + 1e-5f);
  f32x4 g20 = *(const f32x4*)&g2[lq * 4], g21 = *(const f32x4*)&g2[16 + lq * 4];
  f32x4 b20 = *(const f32x4*)&b2[lq * 4], b21 = *(const f32x4*)&b2[16 + lq * 4];
#pragma unroll
  for (int j = 0; j < 4; ++j) {
    p0[j] = (bhalf)((c0[j] - mu) * rs * g20[j] + b20[j]);
    p1[j] = (bhalf)((c1[j] - mu) * rs * g21[j] + b21[j]);
  }
  *(bhalf4*)&s_x[boff + lq * 4] = p0;
  *(bhalf4*)&s_x[boff + 16 + lq * 4] = p1;
}

// ---------------- K1: encoder ----------------
__launch_bounds__(512, 6)
__global__ void k_enc(Ptrs P) {
  __shared__ __align__(16) float s_st[16 * 33];     // 2112B, pad 33 vs bank conflicts
  __shared__ __align__(16) bhalf s_x[144 * 40];     // 11520B
  __shared__ __align__(16) bhalf s_qkv[144 * 100];  // 28800B

  const int tid = threadIdx.x;
  const int wave = tid >> 6, lane = tid & 63;
  const int l15 = lane & 15, lq = lane >> 4;
  const int blk = blockIdx.x;
  const int s0 = blk * 16;

  // stage state
  for (int i = tid; i < 16 * 30; i += 512) {
    int s = i / 30, c = i - s * 30;
    s_st[s * 33 + c] = P.state[(size_t)(s0 + s) * 30 + c];
  }
  __syncthreads();

  // phase 1a: QKV (54 jobs)
#pragma unroll 1
  for (int f = wave; f < 54; f += 8) {
    bool sw = f >= 42;
    int g = sw ? f - 42 : f;
    int t = g / 6, n = g - t * 6;
    bhalf8 bf;
#pragma unroll
    for (int k = 0; k < 8; ++k) bf[k] = (bhalf)0.f;
    if (lq == 0) {
      if (!sw) {
        bf[0] = (bhalf)s_st[l15 * 33 + 2 * t];
        bf[1] = (bhalf)s_st[l15 * 33 + 2 * t + 1];
        bf[2] = (bhalf)1.0f;
      } else {
#pragma unroll
        for (int k = 0; k < 4; ++k) bf[k] = (bhalf)s_st[l15 * 33 + 14 + 4 * t + k];
        bf[4] = (bhalf)1.0f;
      }
    }
    const bhalf* aptr = (sw ? P.A_qs : P.A_qp) + (n * 16 + l15) * 32 + lq * 8;
    int row = (sw ? 112 + t * 16 : t * 16) + l15;
    f32x4 c = {0.f, 0.f, 0.f, 0.f};
    c = mfma16(*(const bhalf8*)aptr, bf, c);
    bhalf4 o;
#pragma unroll
    for (int j = 0; j < 4; ++j) o[j] = (bhalf)c[j];
    *(bhalf4*)&s_qkv[row * 100 + n * 16 + lq * 4] = o;
  }
  // phase 1b: X' (18 jobs)
#pragma unroll 1
  for (int f = wave; f < 18; f += 8) {
    bool sw = f >= 14;
    int g = sw ? f - 14 : f;
    int t = g >> 1, n = g & 1;
    bhalf8 bf;
#pragma unroll
    for (int k = 0; k < 8; ++k) bf[k] = (bhalf)0.f;
    if (lq == 0) {
      if (!sw) {
        bf[0] = (bhalf)s_st[l15 * 33 + 2 * t];
        bf[1] = (bhalf)s_st[l15 * 33 + 2 * t + 1];
        bf[2] = (bhalf)1.0f;
      } else {
#pragma unroll
        for (int k = 0; k < 4; ++k) bf[k] = (bhalf)s_st[l15 * 33 + 14 + 4 * t + k];
        bf[4] = (bhalf)1.0f;
      }
    }
    const bhalf* aptr = (sw ? P.A_xs : P.A_xp) + (n * 16 + l15) * 32 + lq * 8;
    int row = (sw ? 112 + t * 16 : t * 16) + l15;
    f32x4 c = {0.f, 0.f, 0.f, 0.f};
    c = mfma16(*(const bhalf8*)aptr, bf, c);
    bhalf4 o;
#pragma unroll
    for (int j = 0; j < 4; ++j) o[j] = (bhalf)c[j];
    *(bhalf4*)&s_x[row * 40 + n * 16 + lq * 4] = o;
  }
  __syncthreads();

  // attention + phase-D (wave-local)
  {
    const bool sw = (wave == 7);
    const bhalf* wo = sw ? P.w_o2 : P.w_o;
    const bhalf* wf1 = sw ? P.w_f12 : P.w_f1;
    const bhalf* wf2 = sw ? P.w_f22 : P.w_f2;
    const float* g1 = sw ? P.s_g1 : P.p_g1;
    const float* b1 = sw ? P.s_b1 : P.p_b1;
    const float* f1b = sw ? P.s_f1b : P.p_f1b;
    const float* f2b = sw ? P.s_f2b : P.p_f2b;
    const float* g2 = sw ? P.s_g2 : P.p_g2;
    const float* b2 = sw ? P.s_b2 : P.p_b2;
    const int NT = sw ? 2 : 1;
#pragma unroll 1
    for (int tt = 0; tt < NT; ++tt) {
      bhalf8 ov;
      if (!sw) ov = attn_head<7>(s_qkv, 0, wave, l15, lq);
      else     ov = attn_head<2>(s_qkv, 112, tt, l15, lq);
      int row = (sw ? 112 + tt * 16 : wave * 16) + l15;
      phaseD(ov, row, l15, lq, s_x, wo, wf1, wf2, g1, b1, f1b, f2b, g2, b2);
    }
  }

  // store own wave's rows to enc (wave-local, no barrier needed)
  {
    bhalf* dst = P.enc + (size_t)blk * 4608;
    const int nr = (wave == 7) ? 2 : 1;
#pragma unroll 1
    for (int r = 0; r < nr; ++r) {
      int row = (wave < 7 ? wave * 16 : 112 + r * 16) + (lane >> 2);
      int ch = (lane & 3) * 8;
      bhalf8 v = *(const bhalf8*)&s_x[row * 40 + ch];
      *(bhalf8*)&dst[row * 32 + ch] = v;
    }
  }
}

// ---------------- K2: trunk (32 samples/block) ----------------
__launch_bounds__(512, 4)
__global__ void k_trunk(Ptrs P) {
  __shared__ __align__(16) bhalf s_e[288 * 40];   // 23040B; later h1 [32][136]
  __shared__ __align__(16) bhalf s_xc[32 * 408];  // 26112B; later h2 [32][140] f32
  __shared__ __align__(16) float s_st[32 * 9];    // 1152B

  bhalf* h1 = s_e;
  float* h2 = (float*)s_xc;

  const int tid = threadIdx.x;
  const int wave = tid >> 6, lane = tid & 63;
  const int l15 = lane & 15, lq = lane >> 4;
  const int blk = blockIdx.x;
  const int s0 = blk * 32;

  // stage enc (9216 elems) + state cols 22..29
  {
    const bhalf* src = P.enc + (size_t)blk * 9216;
#pragma unroll 1
    for (int i = tid; i < 1152; i += 512) {
      int row = i >> 2, ch = (i & 3) * 8;
      *(bhalf8*)&s_e[row * 40 + ch] = *(const bhalf8*)&src[row * 32 + ch];
    }
    if (tid < 256) {
      int s = tid >> 3, c = tid & 7;
      s_st[s * 9 + c] = P.state[(size_t)(s0 + s) * 30 + 22 + c];
    }
  }
  __syncthreads();

  // out_gemm + st_emb -> s_xc [32][408]; A-frags hoisted across m
  {
    bhalf8 apw[7], asw[2], ae;
#pragma unroll
    for (int t = 0; t < 7; ++t)
      apw[t] = *(const bhalf8*)&P.w_out[(wave * 16 + l15) * 224 + t * 32 + lq * 8];
#pragma unroll
    for (int t = 0; t < 2; ++t)
      asw[t] = *(const bhalf8*)&P.w_out2[(wave * 16 + l15) * 64 + t * 32 + lq * 8];
    ae = *(const bhalf8*)&P.A_e[(wave * 16 + l15) * 32 + lq * 8];
    int oc = wave * 16 + lq * 4;
    f32x4 bp = *(const f32x4*)&P.p_out_b[oc];
    f32x4 bs = *(const f32x4*)&P.s_out_b[oc];
#pragma unroll
    for (int m = 0; m < 2; ++m) {
      int eb = m * 144, xb = m * 16;
      f32x4 c = {0.f, 0.f, 0.f, 0.f};
#pragma unroll
      for (int t = 0; t < 7; ++t)
        c = mfma16(apw[t], *(const bhalf8*)&s_e[(eb + t * 16 + l15) * 40 + lq * 8], c);
      bhalf4 o;
#pragma unroll
      for (int j = 0; j < 4; ++j) o[j] = (bhalf)fmaxf(c[j] + bp[j], 0.f);
      *(bhalf4*)&s_xc[(xb + l15) * 408 + oc] = o;

      c = f32x4{0.f, 0.f, 0.f, 0.f};
#pragma unroll
      for (int t = 0; t < 2; ++t)
        c = mfma16(asw[t], *(const bhalf8*)&s_e[(eb + 112 + t * 16 + l15) * 40 + lq * 8], c);
#pragma unroll
      for (int j = 0; j < 4; ++j) o[j] = (bhalf)fmaxf(c[j] + bs[j], 0.f);
      *(bhalf4*)&s_xc[(xb + l15) * 408 + 128 + oc] = o;

      bhalf8 bf;
#pragma unroll
      for (int k = 0; k < 8; ++k) bf[k] = (bhalf)0.f;
      if (lq == 0) {
#pragma unroll
        for (int k = 0; k < 8; ++k) bf[k] = (bhalf)s_st[(xb + l15) * 9 + k];
      } else if (lq == 1) {
        bf[0] = (bhalf)1.0f;
      }
      c = f32x4{0.f, 0.f, 0.f, 0.f};
      c = mfma16(ae, bf, c);
#pragma unroll
      for (int j = 0; j < 4; ++j) o[j] = (bhalf)fmaxf(c[j], 0.f);
      *(bhalf4*)&s_xc[(xb + l15) * 408 + 256 + oc] = o;
    }
  }
  __syncthreads();

  // d1: A-frags hoisted (12), 2 M-tiles
  {
    bhalf8 ad[12];
#pragma unroll
    for (int ks = 0; ks < 12; ++ks)
      ad[ks] = *(const bhalf8*)&P.w_d1[(wave * 16 + l15) * 384 + ks * 32 + lq * 8];
    int oc = wave * 16 + lq * 4;
    f32x4 bias = *(const f32x4*)&P.d1_b[oc];
#pragma unroll
    for (int m = 0; m < 2; ++m) {
      f32x4 c = {0.f, 0.f, 0.f, 0.f};
#pragma unroll
      for (int ks = 0; ks < 12; ++ks)
        c = mfma16(ad[ks], *(const bhalf8*)&s_xc[(m * 16 + l15) * 408 + ks * 32 + lq * 8], c);
      bhalf4 o;
#pragma unroll
      for (int j = 0; j < 4; ++j) o[j] = (bhalf)fmaxf(c[j] + bias[j], 0.f);
      *(bhalf4*)&h1[(m * 16 + l15) * 136 + oc] = o;
    }
  }
  __syncthreads();

  // d2: A-frags hoisted (4), 2 M-tiles -> h2 f32
  {
    bhalf8 ad[4];
#pragma unroll
    for (int ks = 0; ks < 4; ++ks)
      ad[ks] = *(const bhalf8*)&P.w_d2[(wave * 16 + l15) * 128 + ks * 32 + lq * 8];
    int oc = wave * 16 + lq * 4;
    f32x4 bias = *(const f32x4*)&P.d2_b[oc];
#pragma unroll
    for (int m = 0; m < 2; ++m) {
      f32x4 c = {0.f, 0.f, 0.f, 0.f};
#pragma unroll
      for (int ks = 0; ks < 4; ++ks)
        c = mfma16(ad[ks], *(const bhalf8*)&h1[(m * 16 + l15) * 136 + ks * 32 + lq * 8], c);
      f32x4 o;
#pragma unroll
      for (int j = 0; j < 4; ++j) o[j] = fmaxf(c[j] + bias[j], 0.f);
      *(f32x4*)&h2[(m * 16 + l15) * 140 + oc] = o;
    }
  }
  __syncthreads();

  // heads: 8 lanes/sample, full 128-dot per lane, softmax via 8-lane shfl
  if (tid < 256) {
    int s = tid >> 3, o = tid & 7;
    const float* wrow = (o < 7) ? &P.pi_w[o * 128] : P.v_w;
    const float* hrow = &h2[s * 140];
    float acc = (o < 7) ? P.pi_b[o] : P.v_b[0];
#pragma unroll
    for (int k = 0; k < 32; ++k) {
      f32x4 wv = *(const f32x4*)&wrow[k * 4];
      f32x4 hv = *(const f32x4*)&hrow[k * 4];
#pragma unroll
      for (int j = 0; j < 4; ++j) acc += wv[j] * hv[j];
    }
    float xm = (o < 7) ? acc : -1e30f;
#pragma unroll
    for (int m = 1; m < 8; m <<= 1) xm = fmaxf(xm, __shfl_xor(xm, m));
    float e = (o < 7) ? __expf(acc - xm) : 0.f;
    float se = e;
#pragma unroll
    for (int m = 1; m < 8; m <<= 1) se += __shfl_xor(se, m);
    if (o < 7) P.out[(size_t)(s0 + s) * 7 + o] = e / se;
    else       P.out[917504 + s0 + s] = acc;
  }
}

// ---------------- fallback mono kernel (r8, passing at 410us) ----------------
__launch_bounds__(512, 4)
__global__ void aac_mono(Ptrs P) {
  __shared__ __align__(16) bhalf s_x[144 * 40];
  __shared__ __align__(16) bhalf s_qkv[144 * 100];
  bhalf* xcat = s_qkv;
  bhalf* h1 = s_qkv + 6528;
  float* h2 = (float*)(s_qkv + 8704);
  const int tid = threadIdx.x;
  const int wave = tid >> 6, lane = tid & 63;
  const int l15 = lane & 15, lq = lane >> 4;
  const int s0 = blockIdx.x * 16;
  const float* strow = &P.state[(size_t)(s0 + l15) * 30];
#pragma unroll 1
  for (int f = wave; f < 54; f += 8) {
    bool sw = f >= 42;
    int g = sw ? f - 42 : f;
    int t = g / 6, n = g - t * 6;
    bhalf8 bf;
#pragma unroll
    for (int k = 0; k < 8; ++k) bf[k] = (bhalf)0.f;
    if (lq == 0) {
      if (!sw) {
        f32x2 v = *(const f32x2*)&strow[2 * t];
        bf[0] = (bhalf)v[0]; bf[1] = (bhalf)v[1]; bf[2] = (bhalf)1.0f;
      } else {
        f32x2 v0 = *(const f32x2*)&strow[14 + 4 * t];
        f32x2 v1 = *(const f32x2*)&strow[16 + 4 * t];
        bf[0] = (bhalf)v0[0]; bf[1] = (bhalf)v0[1];
        bf[2] = (bhalf)v1[0]; bf[3] = (bhalf)v1[1];
        bf[4] = (bhalf)1.0f;
      }
    }
    const bhalf* aptr = (sw ? P.A_qs : P.A_qp) + (n * 16 + l15) * 32 + lq * 8;
    int row = (sw ? 112 + t * 16 : t * 16) + l15;
    f32x4 c = {0.f, 0.f, 0.f, 0.f};
    c = mfma16(*(const bhalf8*)aptr, bf, c);
    bhalf4 o;
#pragma unroll
    for (int j = 0; j < 4; ++j) o[j] = (bhalf)c[j];
    *(bhalf4*)&s_qkv[row * 100 + n * 16 + lq * 4] = o;
  }
#pragma unroll 1
  for (int f = wave; f < 18; f += 8) {
    bool sw = f >= 14;
    int g = sw ? f - 14 : f;
    int t = g >> 1, n = g & 1;
    bhalf8 bf;
#pragma unroll
    for (int k = 0; k < 8; ++k) bf[k] = (bhalf)0.f;
    if (lq == 0) {
      if (!sw) {
        f32x2 v = *(const f32x2*)&strow[2 * t];
        bf[0] = (bhalf)v[0]; bf[1] = (bhalf)v[1]; bf[2] = (bhalf)1.0f;
      } else {
        f32x2 v0 = *(const f32x2*)&strow[14 + 4 * t];
        f32x2 v1 = *(const f32x2*)&strow[16 + 4 * t];
        bf[0] = (bhalf)v0[0]; bf[1] = (bhalf)v0[1];
        bf[2] = (bhalf)v1[0]; bf[3] = (bhalf)v1[1];
        bf[4] = (bhalf)1.0f;
      }
    }
    const bhalf* aptr = (sw ? P.A_xs : P.A_xp) + (n * 16 + l15) * 32 + lq * 8;
    int row = (sw ? 112 + t * 16 : t * 16) + l15;
    f32x4 c = {0.f, 0.f, 0.f, 0.f};
    c = mfma16(*(const bhalf8*)aptr, bf, c);
    bhalf4 o;
#pragma unroll
    for (int j = 0; j < 4; ++j) o[j] = (bhalf)c[j];
    *(bhalf4*)&s_x[row * 40 + n * 16 + lq * 4] = o;
  }
  __syncthreads();
  {
    const bool sw = (wave == 7);
    const bhalf* wo = sw ? P.w_o2 : P.w_o;
    const bhalf* wf1 = sw ? P.w_f12 : P.w_f1;
    const bhalf* wf2 = sw ? P.w_f22 : P.w_f2;
    const float* g1 = sw ? P.s_g1 : P.p_g1;
    const float* b1 = sw ? P.s_b1 : P.p_b1;
    const float* f1b = sw ? P.s_f1b : P.p_f1b;
    const float* f2b = sw ? P.s_f2b : P.p_f2b;
    const float* g2 = sw ? P.s_g2 : P.p_g2;
    const float* b2 = sw ? P.s_b2 : P.p_b2;
    const int NT = sw ? 2 : 1;
#pragma unroll 1
    for (int tt = 0; tt < NT; ++tt) {
      bhalf8 ov;
      if (!sw) ov = attn_head<7>(s_qkv, 0, wave, l15, lq);
      else     ov = attn_head<2>(s_qkv, 112, tt, l15, lq);
      int row = (sw ? 112 + tt * 16 : wave * 16) + l15;
      phaseD(ov, row, l15, lq, s_x, wo, wf1, wf2, g1, b1, f1b, f2b, g2, b2);
    }
  }
  __syncthreads();
#pragma unroll 1
  for (int f = wave; f < 24; f += 8) {
    if (f < 8) {
      f32x4 c = {0.f, 0.f, 0.f, 0.f};
#pragma unroll
      for (int t = 0; t < 7; ++t) {
        bhalf8 a = *(const bhalf8*)&P.w_out[(f * 16 + l15) * 224 + t * 32 + lq * 8];
        bhalf8 b = *(const bhalf8*)&s_x[(t * 16 + l15) * 40 + lq * 8];
        c = mfma16(a, b, c);
      }
      int oc = f * 16 + lq * 4;
      f32x4 bias = *(const f32x4*)&P.p_out_b[oc];
      bhalf4 o;
#pragma unroll
      for (int j = 0; j < 4; ++j) o[j] = (bhalf)fmaxf(c[j] + bias[j], 0.f);
      *(bhalf4*)&xcat[l15 * 408 + oc] = o;
    } else if (f < 16) {
      int n = f - 8;
      f32x4 c = {0.f, 0.f, 0.f, 0.f};
#pragma unroll
      for (int t = 0; t < 2; ++t) {
        bhalf8 a = *(const bhalf8*)&P.w_out2[(n * 16 + l15) * 64 + t * 32 + lq * 8];
        bhalf8 b = *(const bhalf8*)&s_x[((7 + t) * 16 + l15) * 40 + lq * 8];
        c = mfma16(a, b, c);
      }
      int oc = n * 16 + lq * 4;
      f32x4 bias = *(const f32x4*)&P.s_out_b[oc];
      bhalf4 o;
#pragma unroll
      for (int j = 0; j < 4; ++j) o[j] = (bhalf)fmaxf(c[j] + bias[j], 0.f);
      *(bhalf4*)&xcat[l15 * 408 + 128 + oc] = o;
    } else {
      int n = f - 16;
      bhalf8 bf;
#pragma unroll
      for (int k = 0; k < 8; ++k) bf[k] = (bhalf)0.f;
      if (lq == 0) {
#pragma unroll
        for (int k = 0; k < 4; ++k) {
          f32x2 v = *(const f32x2*)&strow[22 + 2 * k];
          bf[2 * k] = (bhalf)v[0];
          bf[2 * k + 1] = (bhalf)v[1];
        }
      } else if (lq == 1) {
        bf[0] = (bhalf)1.0f;
      }
      bhalf8 a = *(const bhalf8*)&P.A_e[(n * 16 + l15) * 32 + lq * 8];
      f32x4 c = {0.f, 0.f, 0.f, 0.f};
      c = mfma16(a, bf, c);
      bhalf4 o;
#pragma unroll
      for (int j = 0; j < 4; ++j) o[j] = (bhalf)fmaxf(c[j], 0.f);
      *(bhalf4*)&xcat[l15 * 408 + 256 + n * 16 + lq * 4] = o;
    }
  }
  __syncthreads();
  {
    int n = wave;
    f32x4 c = {0.f, 0.f, 0.f, 0.f};
#pragma unroll
    for (int ks = 0; ks < 12; ++ks) {
      bhalf8 a = *(const bhalf8*)&P.w_d1[(n * 16 + l15) * 384 + ks * 32 + lq * 8];
      bhalf8 b = *(const bhalf8*)&xcat[l15 * 408 + ks * 32 + lq * 8];
      c = mfma16(a, b, c);
    }
    int oc = n * 16 + lq * 4;
    f32x4 bias = *(const f32x4*)&P.d1_b[oc];
    bhalf4 o;
#pragma unroll
    for (int j = 0; j < 4; ++j) o[j] = (bhalf)fmaxf(c[j] + bias[j], 0.f);
    *(bhalf4*)&h1[l15 * 136 + oc] = o;
  }
  __syncthreads();
  {
    int n = wave;
    f32x4 c = {0.f, 0.f, 0.f, 0.f};
#pragma unroll
    for (int ks = 0; ks < 4; ++ks) {
      bhalf8 a = *(const bhalf8*)&P.w_d2[(n * 16 + l15) * 128 + ks * 32 + lq * 8];
      bhalf8 b = *(const bhalf8*)&h1[l15 * 136 + ks * 32 + lq * 8];
      c = mfma16(a, b, c);
    }
    int oc = n * 16 + lq * 4;
    f32x4 bias = *(const f32x4*)&P.d2_b[oc];
    f32x4 o;
#pragma unroll
    for (int j = 0; j < 4; ++j) o[j] = fmaxf(c[j] + bias[j], 0.f);
    *(f32x4*)&h2[l15 * 140 + oc] = o;
  }
  __syncthreads();
  {
    int s = tid >> 5, o = (tid >> 2) & 7, q = tid & 3;
    const float* wrow = (o < 7) ? &P.pi_w[o * 128 + q * 32] : &P.v_w[q * 32];
    const float* hrow = &h2[s * 140 + q * 32];
    float acc = 0.f;
#pragma unroll
    for (int k = 0; k < 8; ++k) {
      f32x4 wv = *(const f32x4*)&wrow[k * 4];
      f32x4 hv = *(const f32x4*)&hrow[k * 4];
#pragma unroll
      for (int j = 0; j < 4; ++j) acc += wv[j] * hv[j];
    }
    acc += __shfl_xor(acc, 1);
    acc += __shfl_xor(acc, 2);
    acc += (o < 7) ? P.pi_b[o] : P.v_b[0];
    float xm = (o < 7) ? acc : -1e30f;
#pragma unroll
    for (int m = 4; m < 32; m <<= 1) xm = fmaxf(xm, __shfl_xor(xm, m));
    float e = (o < 7) ? __expf(acc - xm) : 0.f;
    float se = e;
#pragma unroll
    for (int m = 4; m < 32; m <<= 1) se += __shfl_xor(se, m);
    if (q == 0) {
      if (o < 7) P.out[(size_t)(s0 + s) * 7 + o] = e / se;
      else       P.out[917504 + s0 + s] = acc;
    }
  }
}

// ---------------- launch ----------------
extern "C" void kernel_launch(void* const* d_in, const int* in_sizes, int n_in,
                              void* d_out, int out_size, void* d_ws, size_t ws_size,
                              hipStream_t stream) {
  (void)in_sizes; (void)n_in; (void)out_size;
  const float* const* in = (const float* const*)d_in;
  bhalf* wbf = (bhalf*)d_ws;

  PrepArgs pa;
  const int srcIdx[10] = {5, 9, 11, 15, 21, 25, 27, 31, 35, 37};
  const int lens[10] = {1024, 1024, 1024, 28672, 1024, 1024, 1024, 8192, 49152, 16384};
  const int dsts[10] = {4096, 5120, 6144, 7168, 39936, 40960, 41984, 43008, 55296, 104448};
  for (int i = 0; i < 10; ++i) { pa.src[i] = in[srcIdx[i]]; pa.len[i] = lens[i]; pa.dstOff[i] = dsts[i]; }
  pa.dst = wbf;
  hipLaunchKernelGGL(prep_convert, dim3(424), dim3(256), 0, stream, pa);

  EffArgs ea;
  ea.p_qkv_w = in[3]; ea.p_in_w = in[1]; ea.p_in_b = in[2]; ea.p_qkv_b = in[4]; ea.p_o_b = in[6];
  ea.s_qkv_w = in[19]; ea.s_in_w = in[17]; ea.s_in_b = in[18]; ea.s_qkv_b = in[20]; ea.s_o_b = in[22];
  ea.e_w = in[33]; ea.e_b = in[34];
  ea.dst = wbf;
  hipLaunchKernelGGL(prep_eff, dim3(1), dim3(384), 0, stream, ea);

  Ptrs P;
  P.state = in[0];
  P.p_g1 = in[7];  P.p_b1 = in[8];  P.p_f1b = in[10]; P.p_f2b = in[12];
  P.p_g2 = in[13]; P.p_b2 = in[14]; P.p_out_b = in[16];
  P.s_g1 = in[23]; P.s_b1 = in[24]; P.s_f1b = in[26]; P.s_f2b = in[28];
  P.s_g2 = in[29]; P.s_b2 = in[30]; P.s_out_b = in[32];
  P.d1_b = in[36]; P.d2_b = in[38];
  P.pi_w = in[39]; P.pi_b = in[40]; P.v_w = in[41]; P.v_b = in[42];
  P.A_qp = wbf;          P.A_xp = wbf + 3072;   P.w_o = wbf + 4096;
  P.w_f1 = wbf + 5120;   P.w_f2 = wbf + 6144;   P.w_out = wbf + 7168;
  P.A_qs = wbf + 35840;  P.A_xs = wbf + 38912;  P.w_o2 = wbf + 39936;
  P.w_f12 = wbf + 40960; P.w_f22 = wbf + 41984; P.w_out2 = wbf + 43008;
  P.A_e = wbf + 51200;   P.w_d1 = wbf + 55296;  P.w_d2 = wbf + 104448;
  P.enc = wbf + 131072;  // 75.5 MB region
  P.out = (float*)d_out;

  const size_t WS_NEED = 262144ull + 8192ull * 4608ull * 2ull;  // weights + enc
  if (ws_size >= WS_NEED) {
    hipLaunchKernelGGL(k_enc, dim3(8192), dim3(512), 0, stream, P);
    hipLaunchKernelGGL(k_trunk, dim3(4096), dim3(512), 0, stream, P);
  } else {
    hipLaunchKernelGGL(aac_mono, dim3(8192), dim3(512), 0, stream, P);
  }
}

// Round 10
// 334.615 us; speedup vs baseline: 1.3106x; 1.3106x over previous
//
#include <hip/hip_runtime.h>

// AttentionActorCritic fused forward, MI355X (gfx950).
// Round 10: mono kernel, 32 samples/block, bulk phases (2-6 independent jobs
// per wave per phase = ILP), folded weights, attention-in-regs feeding o-proj,
// LDS 78336B -> 2 blocks/CU, 9 barriers. qkv stride 104 (uniform banks),
// s_x/ff1 stride 32. ff1/xcat/h1/h2 alias dead qkv region.

typedef __bf16 bhalf;
typedef __bf16 bhalf4 __attribute__((ext_vector_type(4)));
typedef __bf16 bhalf8 __attribute__((ext_vector_type(8)));
typedef float f32x4 __attribute__((ext_vector_type(4)));
typedef float f32x2 __attribute__((ext_vector_type(2)));

#define DEV static __device__ __forceinline__

DEV f32x4 mfma16(bhalf8 a, bhalf8 b, f32x4 c) {
  return __builtin_amdgcn_mfma_f32_16x16x32_bf16(a, b, c, 0, 0, 0);
}

// ---------------- pointer bundle ----------------
struct Ptrs {
  const float* state;
  const float *p_g1, *p_b1, *p_f1b, *p_f2b, *p_g2, *p_b2, *p_out_b;
  const float *s_g1, *s_b1, *s_f1b, *s_f2b, *s_g2, *s_b2, *s_out_b;
  const float *d1_b, *d2_b, *pi_w, *pi_b, *v_w, *v_b;
  const bhalf *A_qp, *A_xp, *w_o, *w_f1, *w_f2, *w_out;
  const bhalf *A_qs, *A_xs, *w_o2, *w_f12, *w_f22, *w_out2;
  const bhalf *A_e, *w_d1, *w_d2;
  float* out;
};

// ---------------- prep: fp32 -> bf16 conversions ----------------
struct PrepArgs {
  const float* src[10];
  int len[10];
  int dstOff[10];
  bhalf* dst;
};

__global__ void prep_convert(PrepArgs a) {
  int idx = blockIdx.x * blockDim.x + threadIdx.x;
  int off = 0;
#pragma unroll
  for (int i = 0; i < 10; ++i) {
    int n = a.len[i];
    if (idx >= off && idx < off + n) a.dst[a.dstOff[i] + idx - off] = (bhalf)a.src[i][idx - off];
    off += n;
  }
}

// ---------------- prep: effective (folded) weight matrices ----------------
struct EffArgs {
  const float *p_qkv_w, *p_in_w, *p_in_b, *p_qkv_b, *p_o_b;
  const float *s_qkv_w, *s_in_w, *s_in_b, *s_qkv_b, *s_o_b;
  const float *e_w, *e_b;
  bhalf* dst;
};

__global__ void prep_eff(EffArgs a) {
  int tid = threadIdx.x;
  if (tid < 96) {  // A_qp row o
    const float* wq = a.p_qkv_w + tid * 32;
    float w0 = 0.f, w1 = 0.f, be = 0.f;
    for (int e = 0; e < 32; ++e) {
      w0 += wq[e] * a.p_in_w[e * 2];
      w1 += wq[e] * a.p_in_w[e * 2 + 1];
      be += wq[e] * a.p_in_b[e];
    }
    be += a.p_qkv_b[tid];
    bhalf* d = a.dst + tid * 32;
    for (int k = 0; k < 32; ++k) d[k] = (bhalf)0.f;
    d[0] = (bhalf)w0; d[1] = (bhalf)w1; d[2] = (bhalf)be;
  } else if (tid < 192) {  // A_qs row o
    int o = tid - 96;
    const float* wq = a.s_qkv_w + o * 32;
    float wf[4] = {0.f, 0.f, 0.f, 0.f}, be = 0.f;
    for (int e = 0; e < 32; ++e) {
      for (int f = 0; f < 4; ++f) wf[f] += wq[e] * a.s_in_w[e * 4 + f];
      be += wq[e] * a.s_in_b[e];
    }
    be += a.s_qkv_b[o];
    bhalf* d = a.dst + 35840 + o * 32;
    for (int k = 0; k < 32; ++k) d[k] = (bhalf)0.f;
    for (int f = 0; f < 4; ++f) d[f] = (bhalf)wf[f];
    d[4] = (bhalf)be;
  } else if (tid < 224) {  // A_xp row e
    int e = tid - 192;
    bhalf* d = a.dst + 3072 + e * 32;
    for (int k = 0; k < 32; ++k) d[k] = (bhalf)0.f;
    d[0] = (bhalf)a.p_in_w[e * 2];
    d[1] = (bhalf)a.p_in_w[e * 2 + 1];
    d[2] = (bhalf)(a.p_in_b[e] + a.p_o_b[e]);
  } else if (tid < 256) {  // A_xs row e
    int e = tid - 224;
    bhalf* d = a.dst + 38912 + e * 32;
    for (int k = 0; k < 32; ++k) d[k] = (bhalf)0.f;
    for (int f = 0; f < 4; ++f) d[f] = (bhalf)a.s_in_w[e * 4 + f];
    d[4] = (bhalf)(a.s_in_b[e] + a.s_o_b[e]);
  } else if (tid < 384) {  // A_e row o
    int o = tid - 256;
    bhalf* d = a.dst + 51200 + o * 32;
    for (int k = 0; k < 32; ++k) d[k] = (bhalf)0.f;
    for (int k = 0; k < 8; ++k) d[k] = (bhalf)a.e_w[o * 8 + k];
    d[8] = (bhalf)a.e_b[o];
  }
}

// ---------------- attention: reg output, qkv stride 104, token stride 32 rows ----------------
template <int T>
DEV bhalf8 attn_head(const bhalf* qkv, int rowbase, int a, int s, int h) {
  const bhalf* base = &qkv[(rowbase + s) * 104 + h * 8];
  const int rstep = 32 * 104;
  bhalf8 kf[T];
#pragma unroll
  for (int b = 0; b < T; ++b) kf[b] = *(const bhalf8*)(base + b * rstep + 32);
  bhalf8 qv = *(const bhalf8*)(base + a * rstep);
  float q[8];
#pragma unroll
  for (int i = 0; i < 8; ++i) q[i] = (float)qv[i];
  float sc[T];
  float mx = -1e30f;
#pragma unroll
  for (int b = 0; b < T; ++b) {
    float d = 0.f;
#pragma unroll
    for (int i = 0; i < 8; ++i) d += q[i] * (float)kf[b][i];
    d *= 0.35355339059327378f;  // 1/sqrt(8)
    sc[b] = d;
    mx = fmaxf(mx, d);
  }
  bhalf8 vf[T];
#pragma unroll
  for (int b = 0; b < T; ++b) vf[b] = *(const bhalf8*)(base + b * rstep + 64);
  float sum = 0.f;
#pragma unroll
  for (int b = 0; b < T; ++b) { sc[b] = __expf(sc[b] - mx); sum += sc[b]; }
  float inv = 1.f / sum;
  float o[8] = {0.f, 0.f, 0.f, 0.f, 0.f, 0.f, 0.f, 0.f};
#pragma unroll
  for (int b = 0; b < T; ++b) {
    float w = sc[b] * inv;
#pragma unroll
    for (int i = 0; i < 8; ++i) o[i] += w * (float)vf[b][i];
  }
  bhalf8 ov;
#pragma unroll
  for (int i = 0; i < 8; ++i) ov[i] = (bhalf)o[i];
  return ov;
}

// ---------------- LayerNorm: 2 threads/row, 288 rows, src may == dst ----------------
DEV void ln_pass(int tid, const bhalf* src, bhalf* dst,
                 const float* gp, const float* bp, const float* gs, const float* bs) {
  for (int i = tid; i < 576; i += 512) {
    int row = i >> 1, half = i & 1;
    const bhalf* p = &src[row * 32 + half * 16];
    bhalf8 a0 = *(const bhalf8*)p;
    bhalf8 a1 = *(const bhalf8*)(p + 8);
    float v[16];
#pragma unroll
    for (int k = 0; k < 8; ++k) { v[k] = (float)a0[k]; v[8 + k] = (float)a1[k]; }
    float sum = 0.f, ss = 0.f;
#pragma unroll
    for (int k = 0; k < 16; ++k) { sum += v[k]; ss += v[k] * v[k]; }
    sum += __shfl_xor(sum, 1);
    ss += __shfl_xor(ss, 1);
    float mu = sum * 0.03125f;
    float rs = rsqrtf(ss * 0.03125f - mu * mu + 1e-5f);
    const float* g = (row < 224 ? gp : gs) + half * 16;
    const float* b = (row < 224 ? bp : bs) + half * 16;
    bhalf8 o0, o1;
#pragma unroll
    for (int k = 0; k < 8; ++k) {
      o0[k] = (bhalf)((v[k] - mu) * rs * g[k] + b[k]);
      o1[k] = (bhalf)((v[8 + k] - mu) * rs * g[8 + k] + b[8 + k]);
    }
    bhalf* q = &dst[row * 32 + half * 16];
    *(bhalf8*)q = o0;
    *(bhalf8*)(q + 8) = o1;
  }
}

// ---------------- main fused kernel: 32 samples/block ----------------
__launch_bounds__(512, 4)
__global__ void aac_main(Ptrs P) {
  // 18432 + 59904 = 78336 B -> 2 blocks/CU
  __shared__ __align__(16) bhalf s_x[288 * 32];   // X' / LN outputs (stride 32)
  __shared__ __align__(16) bhalf s_q[288 * 104];  // qkv; aliases ff1/xcat/h1/h2

  bhalf* ff1 = s_q;                    // [288][32]
  bhalf* xcat = s_q;                   // [32][408] elems 0..13055
  bhalf* h1 = s_q + 13056;             // [32][136]
  float* h2 = (float*)(s_q + 17408);   // [32][140] f32

  const int tid = threadIdx.x;
  const int wave = tid >> 6, lane = tid & 63;
  const int l15 = lane & 15, lq = lane >> 4;
  const int s0 = blockIdx.x * 32;

  // ---- phase 1: QKV (108 jobs) + X' (36 jobs); 18/wave, independent ----
  for (int f = wave; f < 144; f += 8) {
    int tile, n;
    bool isQ = f < 108;
    if (isQ) { tile = f / 6; n = f - tile * 6; }
    else { int g = f - 108; tile = g >> 1; n = g & 1; }
    bhalf8 bf;
#pragma unroll
    for (int k = 0; k < 8; ++k) bf[k] = (bhalf)0.f;
    if (lq == 0) {
      if (tile < 14) {
        int t = tile >> 1, s = (tile & 1) * 16 + l15;
        f32x2 v = *(const f32x2*)&P.state[(size_t)(s0 + s) * 30 + 2 * t];
        bf[0] = (bhalf)v[0]; bf[1] = (bhalf)v[1]; bf[2] = (bhalf)1.0f;
      } else {
        int g2 = tile - 14, ts = g2 >> 1, s = (g2 & 1) * 16 + l15;
        const float* st = &P.state[(size_t)(s0 + s) * 30 + 14 + 4 * ts];
        f32x2 v0 = *(const f32x2*)st;
        f32x2 v1 = *(const f32x2*)(st + 2);
        bf[0] = (bhalf)v0[0]; bf[1] = (bhalf)v0[1];
        bf[2] = (bhalf)v1[0]; bf[3] = (bhalf)v1[1];
        bf[4] = (bhalf)1.0f;
      }
    }
    const bhalf* aptr;
    if (isQ) aptr = (tile < 14 ? P.A_qp : P.A_qs) + (n * 16 + l15) * 32 + lq * 8;
    else     aptr = (tile < 14 ? P.A_xp : P.A_xs) + (n * 16 + l15) * 32 + lq * 8;
    f32x4 c = {0.f, 0.f, 0.f, 0.f};
    c = mfma16(*(const bhalf8*)aptr, bf, c);
    bhalf4 o;
#pragma unroll
    for (int j = 0; j < 4; ++j) o[j] = (bhalf)c[j];
    int row = tile * 16 + l15;
    if (isQ) *(bhalf4*)&s_q[row * 104 + n * 16 + lq * 4] = o;
    else     *(bhalf4*)&s_x[row * 32 + n * 16 + lq * 4] = o;
  }
  __syncthreads();  // A

  // ---- attention + o-proj (18 tile-jobs, 2-3/wave); writes s_x in place ----
  for (int tile = wave; tile < 18; tile += 8) {
    bhalf8 ov;
    const bhalf* wo;
    if (tile < 14) {
      ov = attn_head<7>(s_q, 0, tile >> 1, (tile & 1) * 16 + l15, lq);
      wo = P.w_o;
    } else {
      int g = tile - 14;
      ov = attn_head<2>(s_q, 224, g >> 1, (g & 1) * 16 + l15, lq);
      wo = P.w_o2;
    }
    int row = tile * 16 + l15;
    bhalf4 x0 = *(const bhalf4*)&s_x[row * 32 + lq * 4];
    bhalf4 x1 = *(const bhalf4*)&s_x[row * 32 + 16 + lq * 4];
    f32x4 c0, c1;
#pragma unroll
    for (int j = 0; j < 4; ++j) { c0[j] = (float)x0[j]; c1[j] = (float)x1[j]; }
    c0 = mfma16(*(const bhalf8*)&wo[l15 * 32 + lq * 8], ov, c0);
    c1 = mfma16(*(const bhalf8*)&wo[(16 + l15) * 32 + lq * 8], ov, c1);
    bhalf4 p0, p1;
#pragma unroll
    for (int j = 0; j < 4; ++j) { p0[j] = (bhalf)c0[j]; p1[j] = (bhalf)c1[j]; }
    *(bhalf4*)&s_x[row * 32 + lq * 4] = p0;
    *(bhalf4*)&s_x[row * 32 + 16 + lq * 4] = p1;
  }
  __syncthreads();  // B

  // ---- LN1 (in-place s_x) ----
  ln_pass(tid, s_x, s_x, P.p_g1, P.p_b1, P.s_g1, P.s_b1);
  __syncthreads();  // C

  // ---- FF1 + relu -> ff1 (18 tile-jobs) ----
  for (int tile = wave; tile < 18; tile += 8) {
    const bhalf* wf = tile < 14 ? P.w_f1 : P.w_f12;
    const float* fb = tile < 14 ? P.p_f1b : P.s_f1b;
    int row = tile * 16 + l15;
    bhalf8 bfr = *(const bhalf8*)&s_x[row * 32 + lq * 8];
    f32x4 c0 = {0.f, 0.f, 0.f, 0.f}, c1 = {0.f, 0.f, 0.f, 0.f};
    c0 = mfma16(*(const bhalf8*)&wf[l15 * 32 + lq * 8], bfr, c0);
    c1 = mfma16(*(const bhalf8*)&wf[(16 + l15) * 32 + lq * 8], bfr, c1);
    f32x4 b0 = *(const f32x4*)&fb[lq * 4], b1 = *(const f32x4*)&fb[16 + lq * 4];
    bhalf4 p0, p1;
#pragma unroll
    for (int j = 0; j < 4; ++j) {
      p0[j] = (bhalf)fmaxf(c0[j] + b0[j], 0.f);
      p1[j] = (bhalf)fmaxf(c1[j] + b1[j], 0.f);
    }
    *(bhalf4*)&ff1[row * 32 + lq * 4] = p0;
    *(bhalf4*)&ff1[row * 32 + 16 + lq * 4] = p1;
  }
  __syncthreads();  // D

  // ---- FF2 + bias + residual(s_x) -> ff1 in place (18 tile-jobs) ----
  for (int tile = wave; tile < 18; tile += 8) {
    const bhalf* wf = tile < 14 ? P.w_f2 : P.w_f22;
    const float* fb = tile < 14 ? P.p_f2b : P.s_f2b;
    int row = tile * 16 + l15;
    bhalf8 bfr = *(const bhalf8*)&ff1[row * 32 + lq * 8];
    bhalf4 r0 = *(const bhalf4*)&s_x[row * 32 + lq * 4];
    bhalf4 r1 = *(const bhalf4*)&s_x[row * 32 + 16 + lq * 4];
    f32x4 b0 = *(const f32x4*)&fb[lq * 4], b1 = *(const f32x4*)&fb[16 + lq * 4];
    f32x4 c0, c1;
#pragma unroll
    for (int j = 0; j < 4; ++j) {
      c0[j] = b0[j] + (float)r0[j];
      c1[j] = b1[j] + (float)r1[j];
    }
    c0 = mfma16(*(const bhalf8*)&wf[l15 * 32 + lq * 8], bfr, c0);
    c1 = mfma16(*(const bhalf8*)&wf[(16 + l15) * 32 + lq * 8], bfr, c1);
    bhalf4 p0, p1;
#pragma unroll
    for (int j = 0; j < 4; ++j) { p0[j] = (bhalf)c0[j]; p1[j] = (bhalf)c1[j]; }
    *(bhalf4*)&ff1[row * 32 + lq * 4] = p0;
    *(bhalf4*)&ff1[row * 32 + 16 + lq * 4] = p1;
  }
  __syncthreads();  // E

  // ---- LN2: ff1 -> s_x ----
  ln_pass(tid, ff1, s_x, P.p_g2, P.p_b2, P.s_g2, P.s_b2);
  __syncthreads();  // F

  // ---- out_gemm + st_emb -> xcat (48 jobs, 6/wave) ----
  for (int f = wave; f < 48; f += 8) {
    if (f < 16) {  // power out: n = f>>1, m = f&1
      int n = f >> 1, m = f & 1;
      f32x4 c = {0.f, 0.f, 0.f, 0.f};
#pragma unroll
      for (int t = 0; t < 7; ++t) {
        bhalf8 a = *(const bhalf8*)&P.w_out[(n * 16 + l15) * 224 + t * 32 + lq * 8];
        bhalf8 b = *(const bhalf8*)&s_x[(t * 32 + m * 16 + l15) * 32 + lq * 8];
        c = mfma16(a, b, c);
      }
      int oc = n * 16 + lq * 4;
      f32x4 bias = *(const f32x4*)&P.p_out_b[oc];
      bhalf4 o;
#pragma unroll
      for (int j = 0; j < 4; ++j) o[j] = (bhalf)fmaxf(c[j] + bias[j], 0.f);
      *(bhalf4*)&xcat[(m * 16 + l15) * 408 + oc] = o;
    } else if (f < 32) {  // sword out
      int g = f - 16, n = g >> 1, m = g & 1;
      f32x4 c = {0.f, 0.f, 0.f, 0.f};
#pragma unroll
      for (int t = 0; t < 2; ++t) {
        bhalf8 a = *(const bhalf8*)&P.w_out2[(n * 16 + l15) * 64 + t * 32 + lq * 8];
        bhalf8 b = *(const bhalf8*)&s_x[(224 + t * 32 + m * 16 + l15) * 32 + lq * 8];
        c = mfma16(a, b, c);
      }
      int oc = n * 16 + lq * 4;
      f32x4 bias = *(const f32x4*)&P.s_out_b[oc];
      bhalf4 o;
#pragma unroll
      for (int j = 0; j < 4; ++j) o[j] = (bhalf)fmaxf(c[j] + bias[j], 0.f);
      *(bhalf4*)&xcat[(m * 16 + l15) * 408 + 128 + oc] = o;
    } else {  // st_emb
      int g = f - 32, n = g >> 1, m = g & 1;
      int s = m * 16 + l15;
      bhalf8 bf;
#pragma unroll
      for (int k = 0; k < 8; ++k) bf[k] = (bhalf)0.f;
      if (lq == 0) {
        const float* st = &P.state[(size_t)(s0 + s) * 30 + 22];
#pragma unroll
        for (int k = 0; k < 4; ++k) {
          f32x2 v = *(const f32x2*)(st + 2 * k);
          bf[2 * k] = (bhalf)v[0];
          bf[2 * k + 1] = (bhalf)v[1];
        }
      } else if (lq == 1) {
        bf[0] = (bhalf)1.0f;
      }
      bhalf8 a = *(const bhalf8*)&P.A_e[(n * 16 + l15) * 32 + lq * 8];
      f32x4 c = {0.f, 0.f, 0.f, 0.f};
      c = mfma16(a, bf, c);
      bhalf4 o;
#pragma unroll
      for (int j = 0; j < 4; ++j) o[j] = (bhalf)fmaxf(c[j], 0.f);
      *(bhalf4*)&xcat[s * 408 + 256 + n * 16 + lq * 4] = o;
    }
  }
  __syncthreads();  // G

  // ---- d1: 16 jobs (m = f>>3, n = f&7), 2/wave -> h1 ----
  for (int f = wave; f < 16; f += 8) {
    int m = f >> 3, n = f & 7;
    f32x4 c = {0.f, 0.f, 0.f, 0.f};
#pragma unroll
    for (int ks = 0; ks < 12; ++ks) {
      bhalf8 a = *(const bhalf8*)&P.w_d1[(n * 16 + l15) * 384 + ks * 32 + lq * 8];
      bhalf8 b = *(const bhalf8*)&xcat[(m * 16 + l15) * 408 + ks * 32 + lq * 8];
      c = mfma16(a, b, c);
    }
    int oc = n * 16 + lq * 4;
    f32x4 bias = *(const f32x4*)&P.d1_b[oc];
    bhalf4 o;
#pragma unroll
    for (int j = 0; j < 4; ++j) o[j] = (bhalf)fmaxf(c[j] + bias[j], 0.f);
    *(bhalf4*)&h1[(m * 16 + l15) * 136 + oc] = o;
  }
  __syncthreads();  // H

  // ---- d2: 16 jobs, 2/wave -> h2 (f32) ----
  for (int f = wave; f < 16; f += 8) {
    int m = f >> 3, n = f & 7;
    f32x4 c = {0.f, 0.f, 0.f, 0.f};
#pragma unroll
    for (int ks = 0; ks < 4; ++ks) {
      bhalf8 a = *(const bhalf8*)&P.w_d2[(n * 16 + l15) * 128 + ks * 32 + lq * 8];
      bhalf8 b = *(const bhalf8*)&h1[(m * 16 + l15) * 136 + ks * 32 + lq * 8];
      c = mfma16(a, b, c);
    }
    int oc = n * 16 + lq * 4;
    f32x4 bias = *(const f32x4*)&P.d2_b[oc];
    f32x4 o;
#pragma unroll
    for (int j = 0; j < 4; ++j) o[j] = fmaxf(c[j] + bias[j], 0.f);
    *(f32x4*)&h2[(m * 16 + l15) * 140 + oc] = o;
  }
  __syncthreads();  // I

  // ---- heads: 8 lanes/sample (32 samples x 8 outs = 256 threads) ----
  if (tid < 256) {
    int s = tid >> 3, o = tid & 7;
    const float* wrow = (o < 7) ? &P.pi_w[o * 128] : P.v_w;
    const float* hrow = &h2[s * 140];
    float acc = (o < 7) ? P.pi_b[o] : P.v_b[0];
#pragma unroll
    for (int k = 0; k < 32; ++k) {
      f32x4 wv = *(const f32x4*)&wrow[k * 4];
      f32x4 hv = *(const f32x4*)&hrow[k * 4];
#pragma unroll
      for (int j = 0; j < 4; ++j) acc += wv[j] * hv[j];
    }
    float xm = (o < 7) ? acc : -1e30f;
#pragma unroll
    for (int m = 1; m < 8; m <<= 1) xm = fmaxf(xm, __shfl_xor(xm, m));
    float e = (o < 7) ? __expf(acc - xm) : 0.f;
    float se = e;
#pragma unroll
    for (int m = 1; m < 8; m <<= 1) se += __shfl_xor(se, m);
    if (o < 7) P.out[(size_t)(s0 + s) * 7 + o] = e / se;
    else       P.out[917504 + s0 + s] = acc;  // 131072*7
  }
}

// ---------------- launch ----------------
extern "C" void kernel_launch(void* const* d_in, const int* in_sizes, int n_in,
                              void* d_out, int out_size, void* d_ws, size_t ws_size,
                              hipStream_t stream) {
  (void)in_sizes; (void)n_in; (void)out_size; (void)ws_size;
  const float* const* in = (const float* const*)d_in;
  bhalf* wbf = (bhalf*)d_ws;

  PrepArgs pa;
  const int srcIdx[10] = {5, 9, 11, 15, 21, 25, 27, 31, 35, 37};
  const int lens[10] = {1024, 1024, 1024, 28672, 1024, 1024, 1024, 8192, 49152, 16384};
  const int dsts[10] = {4096, 5120, 6144, 7168, 39936, 40960, 41984, 43008, 55296, 104448};
  for (int i = 0; i < 10; ++i) { pa.src[i] = in[srcIdx[i]]; pa.len[i] = lens[i]; pa.dstOff[i] = dsts[i]; }
  pa.dst = wbf;
  hipLaunchKernelGGL(prep_convert, dim3(424), dim3(256), 0, stream, pa);

  EffArgs ea;
  ea.p_qkv_w = in[3]; ea.p_in_w = in[1]; ea.p_in_b = in[2]; ea.p_qkv_b = in[4]; ea.p_o_b = in[6];
  ea.s_qkv_w = in[19]; ea.s_in_w = in[17]; ea.s_in_b = in[18]; ea.s_qkv_b = in[20]; ea.s_o_b = in[22];
  ea.e_w = in[33]; ea.e_b = in[34];
  ea.dst = wbf;
  hipLaunchKernelGGL(prep_eff, dim3(1), dim3(384), 0, stream, ea);

  Ptrs P;
  P.state = in[0];
  P.p_g1 = in[7];  P.p_b1 = in[8];  P.p_f1b = in[10]; P.p_f2b = in[12];
  P.p_g2 = in[13]; P.p_b2 = in[14]; P.p_out_b = in[16];
  P.s_g1 = in[23]; P.s_b1 = in[24]; P.s_f1b = in[26]; P.s_f2b = in[28];
  P.s_g2 = in[29]; P.s_b2 = in[30]; P.s_out_b = in[32];
  P.d1_b = in[36]; P.d2_b = in[38];
  P.pi_w = in[39]; P.pi_b = in[40]; P.v_w = in[41]; P.v_b = in[42];
  P.A_qp = wbf;          P.A_xp = wbf + 3072;   P.w_o = wbf + 4096;
  P.w_f1 = wbf + 5120;   P.w_f2 = wbf + 6144;   P.w_out = wbf + 7168;
  P.A_qs = wbf + 35840;  P.A_xs = wbf + 38912;  P.w_o2 = wbf + 39936;
  P.w_f12 = wbf + 40960; P.w_f22 = wbf + 41984; P.w_out2 = wbf + 43008;
  P.A_e = wbf + 51200;   P.w_d1 = wbf + 55296;  P.w_d2 = wbf + 104448;
  P.out = (float*)d_out;

  hipLaunchKernelGGL(aac_main, dim3(4096), dim3(512), 0, stream, P);  // 131072/32 blocks
}

// Round 11
// 319.129 us; speedup vs baseline: 1.3742x; 1.0485x over previous
//
#include <hip/hip_runtime.h>

// AttentionActorCritic fused forward, MI355X (gfx950).
// Round 11: r10 bulk skeleton + fused encoder tail (attention->o-proj->LN1->
// FF1->FF2->LN2 per tile-chain, 2-3 independent chains/wave, in-register LN,
// wave-local bounces) + XOR-swizzled s_x (kills stride-64B bank conflicts).
// 5 barriers. LDS 78336B -> 2 blocks/CU.

typedef __bf16 bhalf;
typedef __bf16 bhalf4 __attribute__((ext_vector_type(4)));
typedef __bf16 bhalf8 __attribute__((ext_vector_type(8)));
typedef float f32x4 __attribute__((ext_vector_type(4)));
typedef float f32x2 __attribute__((ext_vector_type(2)));

#define DEV static __device__ __forceinline__

DEV f32x4 mfma16(bhalf8 a, bhalf8 b, f32x4 c) {
  return __builtin_amdgcn_mfma_f32_16x16x32_bf16(a, b, c, 0, 0, 0);
}

// s_x swizzle: row stride 32 elems (64B); XOR 16B slots with row&3 to spread banks.
DEV int sxo(int row, int col) { return row * 32 + (col ^ ((row & 3) << 3)); }

// ---------------- pointer bundle ----------------
struct Ptrs {
  const float* state;
  const float *p_g1, *p_b1, *p_f1b, *p_f2b, *p_g2, *p_b2, *p_out_b;
  const float *s_g1, *s_b1, *s_f1b, *s_f2b, *s_g2, *s_b2, *s_out_b;
  const float *d1_b, *d2_b, *pi_w, *pi_b, *v_w, *v_b;
  const bhalf *A_qp, *A_xp, *w_o, *w_f1, *w_f2, *w_out;
  const bhalf *A_qs, *A_xs, *w_o2, *w_f12, *w_f22, *w_out2;
  const bhalf *A_e, *w_d1, *w_d2;
  float* out;
};

// ---------------- prep: fp32 -> bf16 conversions ----------------
struct PrepArgs {
  const float* src[10];
  int len[10];
  int dstOff[10];
  bhalf* dst;
};

__global__ void prep_convert(PrepArgs a) {
  int idx = blockIdx.x * blockDim.x + threadIdx.x;
  int off = 0;
#pragma unroll
  for (int i = 0; i < 10; ++i) {
    int n = a.len[i];
    if (idx >= off && idx < off + n) a.dst[a.dstOff[i] + idx - off] = (bhalf)a.src[i][idx - off];
    off += n;
  }
}

// ---------------- prep: effective (folded) weight matrices ----------------
struct EffArgs {
  const float *p_qkv_w, *p_in_w, *p_in_b, *p_qkv_b, *p_o_b;
  const float *s_qkv_w, *s_in_w, *s_in_b, *s_qkv_b, *s_o_b;
  const float *e_w, *e_b;
  bhalf* dst;
};

__global__ void prep_eff(EffArgs a) {
  int tid = threadIdx.x;
  if (tid < 96) {  // A_qp row o
    const float* wq = a.p_qkv_w + tid * 32;
    float w0 = 0.f, w1 = 0.f, be = 0.f;
    for (int e = 0; e < 32; ++e) {
      w0 += wq[e] * a.p_in_w[e * 2];
      w1 += wq[e] * a.p_in_w[e * 2 + 1];
      be += wq[e] * a.p_in_b[e];
    }
    be += a.p_qkv_b[tid];
    bhalf* d = a.dst + tid * 32;
    for (int k = 0; k < 32; ++k) d[k] = (bhalf)0.f;
    d[0] = (bhalf)w0; d[1] = (bhalf)w1; d[2] = (bhalf)be;
  } else if (tid < 192) {  // A_qs row o
    int o = tid - 96;
    const float* wq = a.s_qkv_w + o * 32;
    float wf[4] = {0.f, 0.f, 0.f, 0.f}, be = 0.f;
    for (int e = 0; e < 32; ++e) {
      for (int f = 0; f < 4; ++f) wf[f] += wq[e] * a.s_in_w[e * 4 + f];
      be += wq[e] * a.s_in_b[e];
    }
    be += a.s_qkv_b[o];
    bhalf* d = a.dst + 35840 + o * 32;
    for (int k = 0; k < 32; ++k) d[k] = (bhalf)0.f;
    for (int f = 0; f < 4; ++f) d[f] = (bhalf)wf[f];
    d[4] = (bhalf)be;
  } else if (tid < 224) {  // A_xp row e
    int e = tid - 192;
    bhalf* d = a.dst + 3072 + e * 32;
    for (int k = 0; k < 32; ++k) d[k] = (bhalf)0.f;
    d[0] = (bhalf)a.p_in_w[e * 2];
    d[1] = (bhalf)a.p_in_w[e * 2 + 1];
    d[2] = (bhalf)(a.p_in_b[e] + a.p_o_b[e]);
  } else if (tid < 256) {  // A_xs row e
    int e = tid - 224;
    bhalf* d = a.dst + 38912 + e * 32;
    for (int k = 0; k < 32; ++k) d[k] = (bhalf)0.f;
    for (int f = 0; f < 4; ++f) d[f] = (bhalf)a.s_in_w[e * 4 + f];
    d[4] = (bhalf)(a.s_in_b[e] + a.s_o_b[e]);
  } else if (tid < 384) {  // A_e row o
    int o = tid - 256;
    bhalf* d = a.dst + 51200 + o * 32;
    for (int k = 0; k < 32; ++k) d[k] = (bhalf)0.f;
    for (int k = 0; k < 8; ++k) d[k] = (bhalf)a.e_w[o * 8 + k];
    d[8] = (bhalf)a.e_b[o];
  }
}

// ---------------- attention: reg output, qkv stride 104, token stride 32 rows ----------------
template <int T>
DEV bhalf8 attn_head(const bhalf* qkv, int rowbase, int a, int s, int h) {
  const bhalf* base = &qkv[(rowbase + s) * 104 + h * 8];
  const int rstep = 32 * 104;
  bhalf8 kf[T];
#pragma unroll
  for (int b = 0; b < T; ++b) kf[b] = *(const bhalf8*)(base + b * rstep + 32);
  bhalf8 qv = *(const bhalf8*)(base + a * rstep);
  float q[8];
#pragma unroll
  for (int i = 0; i < 8; ++i) q[i] = (float)qv[i];
  float sc[T];
  float mx = -1e30f;
#pragma unroll
  for (int b = 0; b < T; ++b) {
    float d = 0.f;
#pragma unroll
    for (int i = 0; i < 8; ++i) d += q[i] * (float)kf[b][i];
    d *= 0.35355339059327378f;  // 1/sqrt(8)
    sc[b] = d;
    mx = fmaxf(mx, d);
  }
  bhalf8 vf[T];
#pragma unroll
  for (int b = 0; b < T; ++b) vf[b] = *(const bhalf8*)(base + b * rstep + 64);
  float sum = 0.f;
#pragma unroll
  for (int b = 0; b < T; ++b) { sc[b] = __expf(sc[b] - mx); sum += sc[b]; }
  float inv = 1.f / sum;
  float o[8] = {0.f, 0.f, 0.f, 0.f, 0.f, 0.f, 0.f, 0.f};
#pragma unroll
  for (int b = 0; b < T; ++b) {
    float w = sc[b] * inv;
#pragma unroll
    for (int i = 0; i < 8; ++i) o[i] += w * (float)vf[b][i];
  }
  bhalf8 ov;
#pragma unroll
  for (int i = 0; i < 8; ++i) ov[i] = (bhalf)o[i];
  return ov;
}

// ---------------- fused encoder tile-chain (r8 phaseD math, swizzled s_x) ----------------
template <int T>
DEV void enc_tile(const bhalf* s_q, bhalf* s_x, int tile, int rowbase, int a,
                  int l15, int lq,
                  const bhalf* wo, const bhalf* wf1, const bhalf* wf2,
                  const float* g1, const float* b1, const float* f1b,
                  const float* f2b, const float* g2, const float* b2) {
  const int s = (tile & 1) * 16 + l15;
  bhalf8 ov = attn_head<T>(s_q, rowbase, a, s, lq);
  const int row = tile * 16 + l15;
  // o-proj with C-init = X' (includes o_b)
  bhalf4 x0 = *(const bhalf4*)&s_x[sxo(row, lq * 4)];
  bhalf4 x1 = *(const bhalf4*)&s_x[sxo(row, 16 + lq * 4)];
  f32x4 c0, c1;
#pragma unroll
  for (int j = 0; j < 4; ++j) { c0[j] = (float)x0[j]; c1[j] = (float)x1[j]; }
  c0 = mfma16(*(const bhalf8*)&wo[l15 * 32 + lq * 8], ov, c0);
  c1 = mfma16(*(const bhalf8*)&wo[(16 + l15) * 32 + lq * 8], ov, c1);
  // LN1 in-register (row spread over lanes {l15, +16, +32, +48})
  float sum = 0.f, ss = 0.f;
#pragma unroll
  for (int j = 0; j < 4; ++j) { sum += c0[j] + c1[j]; ss += c0[j] * c0[j] + c1[j] * c1[j]; }
  sum += __shfl_xor(sum, 16); sum += __shfl_xor(sum, 32);
  ss += __shfl_xor(ss, 16); ss += __shfl_xor(ss, 32);
  float mu = sum * 0.03125f;
  float rs = rsqrtf(ss * 0.03125f - mu * mu + 1e-5f);
  f32x4 gg0 = *(const f32x4*)&g1[lq * 4], gg1 = *(const f32x4*)&g1[16 + lq * 4];
  f32x4 hb0 = *(const f32x4*)&b1[lq * 4], hb1 = *(const f32x4*)&b1[16 + lq * 4];
  float xn[8];
#pragma unroll
  for (int j = 0; j < 4; ++j) {
    xn[j] = (c0[j] - mu) * rs * gg0[j] + hb0[j];
    xn[4 + j] = (c1[j] - mu) * rs * gg1[j] + hb1[j];
  }
  bhalf4 p0, p1;
#pragma unroll
  for (int j = 0; j < 4; ++j) { p0[j] = (bhalf)xn[j]; p1[j] = (bhalf)xn[4 + j]; }
  *(bhalf4*)&s_x[sxo(row, lq * 4)] = p0;
  *(bhalf4*)&s_x[sxo(row, 16 + lq * 4)] = p1;
  bhalf8 bfr = *(const bhalf8*)&s_x[sxo(row, lq * 8)];
  // FF1 + relu (bounce via s_x; residual xn stays in regs)
  c0 = f32x4{0.f, 0.f, 0.f, 0.f};
  c1 = f32x4{0.f, 0.f, 0.f, 0.f};
  c0 = mfma16(*(const bhalf8*)&wf1[l15 * 32 + lq * 8], bfr, c0);
  c1 = mfma16(*(const bhalf8*)&wf1[(16 + l15) * 32 + lq * 8], bfr, c1);
  f32x4 fb0 = *(const f32x4*)&f1b[lq * 4], fb1 = *(const f32x4*)&f1b[16 + lq * 4];
#pragma unroll
  for (int j = 0; j < 4; ++j) {
    p0[j] = (bhalf)fmaxf(c0[j] + fb0[j], 0.f);
    p1[j] = (bhalf)fmaxf(c1[j] + fb1[j], 0.f);
  }
  *(bhalf4*)&s_x[sxo(row, lq * 4)] = p0;
  *(bhalf4*)&s_x[sxo(row, 16 + lq * 4)] = p1;
  bfr = *(const bhalf8*)&s_x[sxo(row, lq * 8)];
  // FF2 with C-init = xn + f2b (residual + bias), then LN2 -> s_x
  f32x4 f20 = *(const f32x4*)&f2b[lq * 4], f21 = *(const f32x4*)&f2b[16 + lq * 4];
#pragma unroll
  for (int j = 0; j < 4; ++j) { c0[j] = xn[j] + f20[j]; c1[j] = xn[4 + j] + f21[j]; }
  c0 = mfma16(*(const bhalf8*)&wf2[l15 * 32 + lq * 8], bfr, c0);
  c1 = mfma16(*(const bhalf8*)&wf2[(16 + l15) * 32 + lq * 8], bfr, c1);
  sum = 0.f; ss = 0.f;
#pragma unroll
  for (int j = 0; j < 4; ++j) { sum += c0[j] + c1[j]; ss += c0[j] * c0[j] + c1[j] * c1[j]; }
  sum += __shfl_xor(sum, 16); sum += __shfl_xor(sum, 32);
  ss += __shfl_xor(ss, 16); ss += __shfl_xor(ss, 32);
  mu = sum * 0.03125f;
  rs = rsqrtf(ss * 0.03125f - mu * mu + 1e-5f);
  f32x4 g20 = *(const f32x4*)&g2[lq * 4], g21 = *(const f32x4*)&g2[16 + lq * 4];
  f32x4 b20 = *(const f32x4*)&b2[lq * 4], b21 = *(const f32x4*)&b2[16 + lq * 4];
#pragma unroll
  for (int j = 0; j < 4; ++j) {
    p0[j] = (bhalf)((c0[j] - mu) * rs * g20[j] + b20[j]);
    p1[j] = (bhalf)((c1[j] - mu) * rs * g21[j] + b21[j]);
  }
  *(bhalf4*)&s_x[sxo(row, lq * 4)] = p0;
  *(bhalf4*)&s_x[sxo(row, 16 + lq * 4)] = p1;
}

// ---------------- main fused kernel: 32 samples/block ----------------
__launch_bounds__(512, 4)
__global__ void aac_main(Ptrs P) {
  // 18432 + 59904 = 78336 B -> 2 blocks/CU
  __shared__ __align__(16) bhalf s_x[288 * 32];   // X' / LN2 out, swizzled cols
  __shared__ __align__(16) bhalf s_q[288 * 104];  // qkv; aliases xcat/h1/h2

  bhalf* xcat = s_q;                   // [32][408] elems 0..13055
  bhalf* h1 = s_q + 13056;             // [32][136]
  float* h2 = (float*)(s_q + 17408);   // [32][140] f32

  const int tid = threadIdx.x;
  const int wave = tid >> 6, lane = tid & 63;
  const int l15 = lane & 15, lq = lane >> 4;
  const int s0 = blockIdx.x * 32;

  // ---- phase 1: QKV (108 jobs) + X' (36 jobs); 18/wave ----
  for (int f = wave; f < 144; f += 8) {
    int tile, n;
    bool isQ = f < 108;
    if (isQ) { tile = f / 6; n = f - tile * 6; }
    else { int g = f - 108; tile = g >> 1; n = g & 1; }
    bhalf8 bf;
#pragma unroll
    for (int k = 0; k < 8; ++k) bf[k] = (bhalf)0.f;
    if (lq == 0) {
      if (tile < 14) {
        int t = tile >> 1, s = (tile & 1) * 16 + l15;
        f32x2 v = *(const f32x2*)&P.state[(size_t)(s0 + s) * 30 + 2 * t];
        bf[0] = (bhalf)v[0]; bf[1] = (bhalf)v[1]; bf[2] = (bhalf)1.0f;
      } else {
        int g2 = tile - 14, ts = g2 >> 1, s = (g2 & 1) * 16 + l15;
        const float* st = &P.state[(size_t)(s0 + s) * 30 + 14 + 4 * ts];
        f32x2 v0 = *(const f32x2*)st;
        f32x2 v1 = *(const f32x2*)(st + 2);
        bf[0] = (bhalf)v0[0]; bf[1] = (bhalf)v0[1];
        bf[2] = (bhalf)v1[0]; bf[3] = (bhalf)v1[1];
        bf[4] = (bhalf)1.0f;
      }
    }
    const bhalf* aptr;
    if (isQ) aptr = (tile < 14 ? P.A_qp : P.A_qs) + (n * 16 + l15) * 32 + lq * 8;
    else     aptr = (tile < 14 ? P.A_xp : P.A_xs) + (n * 16 + l15) * 32 + lq * 8;
    f32x4 c = {0.f, 0.f, 0.f, 0.f};
    c = mfma16(*(const bhalf8*)aptr, bf, c);
    bhalf4 o;
#pragma unroll
    for (int j = 0; j < 4; ++j) o[j] = (bhalf)c[j];
    int row = tile * 16 + l15;
    if (isQ) *(bhalf4*)&s_q[row * 104 + n * 16 + lq * 4] = o;
    else     *(bhalf4*)&s_x[sxo(row, n * 16 + lq * 4)] = o;
  }
  __syncthreads();  // A

  // ---- fused encoder: 18 tile-chains, 2-3 independent chains per wave ----
  {
    // chain 1: power tile = wave (tiles 0-7)
    enc_tile<7>(s_q, s_x, wave, 0, wave >> 1, l15, lq,
                P.w_o, P.w_f1, P.w_f2, P.p_g1, P.p_b1, P.p_f1b, P.p_f2b, P.p_g2, P.p_b2);
    // chain 2: tile = wave+8 (power for waves 0-5, sword for 6,7)
    if (wave < 6) {
      enc_tile<7>(s_q, s_x, wave + 8, 0, (wave + 8) >> 1, l15, lq,
                  P.w_o, P.w_f1, P.w_f2, P.p_g1, P.p_b1, P.p_f1b, P.p_f2b, P.p_g2, P.p_b2);
    } else {
      enc_tile<2>(s_q, s_x, wave + 8, 224, (wave + 8 - 14) >> 1, l15, lq,
                  P.w_o2, P.w_f12, P.w_f22, P.s_g1, P.s_b1, P.s_f1b, P.s_f2b, P.s_g2, P.s_b2);
    }
    // chain 3: sword tiles 16,17 on waves 0,1
    if (wave < 2) {
      enc_tile<2>(s_q, s_x, 16 + wave, 224, (16 + wave - 14) >> 1, l15, lq,
                  P.w_o2, P.w_f12, P.w_f22, P.s_g1, P.s_b1, P.s_f1b, P.s_f2b, P.s_g2, P.s_b2);
    }
  }
  __syncthreads();  // B

  // ---- out_gemm + st_emb -> xcat (48 jobs, 6/wave, kind compile-time per k) ----
#pragma unroll
  for (int k = 0; k < 2; ++k) {  // power out: f = wave + 8k
    int f = wave + 8 * k;
    int n = f >> 1, m = f & 1;
    f32x4 c = {0.f, 0.f, 0.f, 0.f};
#pragma unroll
    for (int t = 0; t < 7; ++t) {
      bhalf8 a = *(const bhalf8*)&P.w_out[(n * 16 + l15) * 224 + t * 32 + lq * 8];
      bhalf8 b = *(const bhalf8*)&s_x[sxo(t * 32 + m * 16 + l15, lq * 8)];
      c = mfma16(a, b, c);
    }
    int oc = n * 16 + lq * 4;
    f32x4 bias = *(const f32x4*)&P.p_out_b[oc];
    bhalf4 o;
#pragma unroll
    for (int j = 0; j < 4; ++j) o[j] = (bhalf)fmaxf(c[j] + bias[j], 0.f);
    *(bhalf4*)&xcat[(m * 16 + l15) * 408 + oc] = o;
  }
#pragma unroll
  for (int k = 0; k < 2; ++k) {  // sword out: g = wave + 8k
    int g = wave + 8 * k;
    int n = g >> 1, m = g & 1;
    f32x4 c = {0.f, 0.f, 0.f, 0.f};
#pragma unroll
    for (int t = 0; t < 2; ++t) {
      bhalf8 a = *(const bhalf8*)&P.w_out2[(n * 16 + l15) * 64 + t * 32 + lq * 8];
      bhalf8 b = *(const bhalf8*)&s_x[sxo(224 + t * 32 + m * 16 + l15, lq * 8)];
      c = mfma16(a, b, c);
    }
    int oc = n * 16 + lq * 4;
    f32x4 bias = *(const f32x4*)&P.s_out_b[oc];
    bhalf4 o;
#pragma unroll
    for (int j = 0; j < 4; ++j) o[j] = (bhalf)fmaxf(c[j] + bias[j], 0.f);
    *(bhalf4*)&xcat[(m * 16 + l15) * 408 + 128 + oc] = o;
  }
#pragma unroll
  for (int k = 0; k < 2; ++k) {  // st_emb
    int g = wave + 8 * k;
    int n = g >> 1, m = g & 1;
    int s = m * 16 + l15;
    bhalf8 bf;
#pragma unroll
    for (int kk = 0; kk < 8; ++kk) bf[kk] = (bhalf)0.f;
    if (lq == 0) {
      const float* st = &P.state[(size_t)(s0 + s) * 30 + 22];
#pragma unroll
      for (int kk = 0; kk < 4; ++kk) {
        f32x2 v = *(const f32x2*)(st + 2 * kk);
        bf[2 * kk] = (bhalf)v[0];
        bf[2 * kk + 1] = (bhalf)v[1];
      }
    } else if (lq == 1) {
      bf[0] = (bhalf)1.0f;
    }
    bhalf8 a = *(const bhalf8*)&P.A_e[(n * 16 + l15) * 32 + lq * 8];
    f32x4 c = {0.f, 0.f, 0.f, 0.f};
    c = mfma16(a, bf, c);
    bhalf4 o;
#pragma unroll
    for (int j = 0; j < 4; ++j) o[j] = (bhalf)fmaxf(c[j], 0.f);
    *(bhalf4*)&xcat[s * 408 + 256 + n * 16 + lq * 4] = o;
  }
  __syncthreads();  // C

  // ---- d1: 2 independent jobs/wave (m=0,1; n=wave) -> h1 ----
#pragma unroll
  for (int m = 0; m < 2; ++m) {
    int n = wave;
    f32x4 c = {0.f, 0.f, 0.f, 0.f};
#pragma unroll
    for (int ks = 0; ks < 12; ++ks) {
      bhalf8 a = *(const bhalf8*)&P.w_d1[(n * 16 + l15) * 384 + ks * 32 + lq * 8];
      bhalf8 b = *(const bhalf8*)&xcat[(m * 16 + l15) * 408 + ks * 32 + lq * 8];
      c = mfma16(a, b, c);
    }
    int oc = n * 16 + lq * 4;
    f32x4 bias = *(const f32x4*)&P.d1_b[oc];
    bhalf4 o;
#pragma unroll
    for (int j = 0; j < 4; ++j) o[j] = (bhalf)fmaxf(c[j] + bias[j], 0.f);
    *(bhalf4*)&h1[(m * 16 + l15) * 136 + oc] = o;
  }
  __syncthreads();  // D

  // ---- d2: 2 independent jobs/wave -> h2 (f32) ----
#pragma unroll
  for (int m = 0; m < 2; ++m) {
    int n = wave;
    f32x4 c = {0.f, 0.f, 0.f, 0.f};
#pragma unroll
    for (int ks = 0; ks < 4; ++ks) {
      bhalf8 a = *(const bhalf8*)&P.w_d2[(n * 16 + l15) * 128 + ks * 32 + lq * 8];
      bhalf8 b = *(const bhalf8*)&h1[(m * 16 + l15) * 136 + ks * 32 + lq * 8];
      c = mfma16(a, b, c);
    }
    int oc = n * 16 + lq * 4;
    f32x4 bias = *(const f32x4*)&P.d2_b[oc];
    f32x4 o;
#pragma unroll
    for (int j = 0; j < 4; ++j) o[j] = fmaxf(c[j] + bias[j], 0.f);
    *(f32x4*)&h2[(m * 16 + l15) * 140 + oc] = o;
  }
  __syncthreads();  // E

  // ---- heads: 8 lanes/sample (32 samples x 8 outs = 256 threads) ----
  if (tid < 256) {
    int s = tid >> 3, o = tid & 7;
    const float* wrow = (o < 7) ? &P.pi_w[o * 128] : P.v_w;
    const float* hrow = &h2[s * 140];
    float acc = (o < 7) ? P.pi_b[o] : P.v_b[0];
#pragma unroll
    for (int k = 0; k < 32; ++k) {
      f32x4 wv = *(const f32x4*)&wrow[k * 4];
      f32x4 hv = *(const f32x4*)&hrow[k * 4];
#pragma unroll
      for (int j = 0; j < 4; ++j) acc += wv[j] * hv[j];
    }
    float xm = (o < 7) ? acc : -1e30f;
#pragma unroll
    for (int m = 1; m < 8; m <<= 1) xm = fmaxf(xm, __shfl_xor(xm, m));
    float e = (o < 7) ? __expf(acc - xm) : 0.f;
    float se = e;
#pragma unroll
    for (int m = 1; m < 8; m <<= 1) se += __shfl_xor(se, m);
    if (o < 7) P.out[(size_t)(s0 + s) * 7 + o] = e / se;
    else       P.out[917504 + s0 + s] = acc;  // 131072*7
  }
}

// ---------------- launch ----------------
extern "C" void kernel_launch(void* const* d_in, const int* in_sizes, int n_in,
                              void* d_out, int out_size, void* d_ws, size_t ws_size,
                              hipStream_t stream) {
  (void)in_sizes; (void)n_in; (void)out_size; (void)ws_size;
  const float* const* in = (const float* const*)d_in;
  bhalf* wbf = (bhalf*)d_ws;

  PrepArgs pa;
  const int srcIdx[10] = {5, 9, 11, 15, 21, 25, 27, 31, 35, 37};
  const int lens[10] = {1024, 1024, 1024, 28672, 1024, 1024, 1024, 8192, 49152, 16384};
  const int dsts[10] = {4096, 5120, 6144, 7168, 39936, 40960, 41984, 43008, 55296, 104448};
  for (int i = 0; i < 10; ++i) { pa.src[i] = in[srcIdx[i]]; pa.len[i] = lens[i]; pa.dstOff[i] = dsts[i]; }
  pa.dst = wbf;
  hipLaunchKernelGGL(prep_convert, dim3(424), dim3(256), 0, stream, pa);

  EffArgs ea;
  ea.p_qkv_w = in[3]; ea.p_in_w = in[1]; ea.p_in_b = in[2]; ea.p_qkv_b = in[4]; ea.p_o_b = in[6];
  ea.s_qkv_w = in[19]; ea.s_in_w = in[17]; ea.s_in_b = in[18]; ea.s_qkv_b = in[20]; ea.s_o_b = in[22];
  ea.e_w = in[33]; ea.e_b = in[34];
  ea.dst = wbf;
  hipLaunchKernelGGL(prep_eff, dim3(1), dim3(384), 0, stream, ea);

  Ptrs P;
  P.state = in[0];
  P.p_g1 = in[7];  P.p_b1 = in[8];  P.p_f1b = in[10]; P.p_f2b = in[12];
  P.p_g2 = in[13]; P.p_b2 = in[14]; P.p_out_b = in[16];
  P.s_g1 = in[23]; P.s_b1 = in[24]; P.s_f1b = in[26]; P.s_f2b = in[28];
  P.s_g2 = in[29]; P.s_b2 = in[30]; P.s_out_b = in[32];
  P.d1_b = in[36]; P.d2_b = in[38];
  P.pi_w = in[39]; P.pi_b = in[40]; P.v_w = in[41]; P.v_b = in[42];
  P.A_qp = wbf;          P.A_xp = wbf + 3072;   P.w_o = wbf + 4096;
  P.w_f1 = wbf + 5120;   P.w_f2 = wbf + 6144;   P.w_out = wbf + 7168;
  P.A_qs = wbf + 35840;  P.A_xs = wbf + 38912;  P.w_o2 = wbf + 39936;
  P.w_f12 = wbf + 40960; P.w_f22 = wbf + 41984; P.w_out2 = wbf + 43008;
  P.A_e = wbf + 51200;   P.w_d1 = wbf + 55296;  P.w_d2 = wbf + 104448;
  P.out = (float*)d_out;

  hipLaunchKernelGGL(aac_main, dim3(4096), dim3(512), 0, stream, P);  // 131072/32 blocks
}

// Round 12
// 284.776 us; speedup vs baseline: 1.5400x; 1.1206x over previous
//
#include <hip/hip_runtime.h>

// AttentionActorCritic fused forward, MI355X (gfx950).
// Round 12: r11 + phase1 restructured per-wave-per-tile (one bf build -> 6 QKV
// + 2 X' MFMAs); X' stays in REGISTERS as o-proj C-init (f32, no LDS trip).
// s_x written only by LN2. 5 barriers, swizzled s_x, 78336B LDS.

typedef __bf16 bhalf;
typedef __bf16 bhalf4 __attribute__((ext_vector_type(4)));
typedef __bf16 bhalf8 __attribute__((ext_vector_type(8)));
typedef float f32x4 __attribute__((ext_vector_type(4)));
typedef float f32x2 __attribute__((ext_vector_type(2)));

#define DEV static __device__ __forceinline__

DEV f32x4 mfma16(bhalf8 a, bhalf8 b, f32x4 c) {
  return __builtin_amdgcn_mfma_f32_16x16x32_bf16(a, b, c, 0, 0, 0);
}

// s_x swizzle: row stride 32 elems (64B); XOR 16B slots with row&3.
DEV int sxo(int row, int col) { return row * 32 + (col ^ ((row & 3) << 3)); }

// ---------------- pointer bundle ----------------
struct Ptrs {
  const float* state;
  const float *p_g1, *p_b1, *p_f1b, *p_f2b, *p_g2, *p_b2, *p_out_b;
  const float *s_g1, *s_b1, *s_f1b, *s_f2b, *s_g2, *s_b2, *s_out_b;
  const float *d1_b, *d2_b, *pi_w, *pi_b, *v_w, *v_b;
  const bhalf *A_qp, *A_xp, *w_o, *w_f1, *w_f2, *w_out;
  const bhalf *A_qs, *A_xs, *w_o2, *w_f12, *w_f22, *w_out2;
  const bhalf *A_e, *w_d1, *w_d2;
  float* out;
};

// ---------------- prep: fp32 -> bf16 conversions ----------------
struct PrepArgs {
  const float* src[10];
  int len[10];
  int dstOff[10];
  bhalf* dst;
};

__global__ void prep_convert(PrepArgs a) {
  int idx = blockIdx.x * blockDim.x + threadIdx.x;
  int off = 0;
#pragma unroll
  for (int i = 0; i < 10; ++i) {
    int n = a.len[i];
    if (idx >= off && idx < off + n) a.dst[a.dstOff[i] + idx - off] = (bhalf)a.src[i][idx - off];
    off += n;
  }
}

// ---------------- prep: effective (folded) weight matrices ----------------
struct EffArgs {
  const float *p_qkv_w, *p_in_w, *p_in_b, *p_qkv_b, *p_o_b;
  const float *s_qkv_w, *s_in_w, *s_in_b, *s_qkv_b, *s_o_b;
  const float *e_w, *e_b;
  bhalf* dst;
};

__global__ void prep_eff(EffArgs a) {
  int tid = threadIdx.x;
  if (tid < 96) {  // A_qp row o
    const float* wq = a.p_qkv_w + tid * 32;
    float w0 = 0.f, w1 = 0.f, be = 0.f;
    for (int e = 0; e < 32; ++e) {
      w0 += wq[e] * a.p_in_w[e * 2];
      w1 += wq[e] * a.p_in_w[e * 2 + 1];
      be += wq[e] * a.p_in_b[e];
    }
    be += a.p_qkv_b[tid];
    bhalf* d = a.dst + tid * 32;
    for (int k = 0; k < 32; ++k) d[k] = (bhalf)0.f;
    d[0] = (bhalf)w0; d[1] = (bhalf)w1; d[2] = (bhalf)be;
  } else if (tid < 192) {  // A_qs row o
    int o = tid - 96;
    const float* wq = a.s_qkv_w + o * 32;
    float wf[4] = {0.f, 0.f, 0.f, 0.f}, be = 0.f;
    for (int e = 0; e < 32; ++e) {
      for (int f = 0; f < 4; ++f) wf[f] += wq[e] * a.s_in_w[e * 4 + f];
      be += wq[e] * a.s_in_b[e];
    }
    be += a.s_qkv_b[o];
    bhalf* d = a.dst + 35840 + o * 32;
    for (int k = 0; k < 32; ++k) d[k] = (bhalf)0.f;
    for (int f = 0; f < 4; ++f) d[f] = (bhalf)wf[f];
    d[4] = (bhalf)be;
  } else if (tid < 224) {  // A_xp row e
    int e = tid - 192;
    bhalf* d = a.dst + 3072 + e * 32;
    for (int k = 0; k < 32; ++k) d[k] = (bhalf)0.f;
    d[0] = (bhalf)a.p_in_w[e * 2];
    d[1] = (bhalf)a.p_in_w[e * 2 + 1];
    d[2] = (bhalf)(a.p_in_b[e] + a.p_o_b[e]);
  } else if (tid < 256) {  // A_xs row e
    int e = tid - 224;
    bhalf* d = a.dst + 38912 + e * 32;
    for (int k = 0; k < 32; ++k) d[k] = (bhalf)0.f;
    for (int f = 0; f < 4; ++f) d[f] = (bhalf)a.s_in_w[e * 4 + f];
    d[4] = (bhalf)(a.s_in_b[e] + a.s_o_b[e]);
  } else if (tid < 384) {  // A_e row o
    int o = tid - 256;
    bhalf* d = a.dst + 51200 + o * 32;
    for (int k = 0; k < 32; ++k) d[k] = (bhalf)0.f;
    for (int k = 0; k < 8; ++k) d[k] = (bhalf)a.e_w[o * 8 + k];
    d[8] = (bhalf)a.e_b[o];
  }
}

// ---------------- phase-1 tile: one bf build -> 6 QKV (LDS) + 2 X' (regs) ----------------
DEV void p1_tile(const Ptrs& P, bhalf* s_q, int tile, int s0, int l15, int lq,
                 f32x4& cx0, f32x4& cx1) {
  const bool sw = tile >= 14;
  bhalf8 bf;
#pragma unroll
  for (int k = 0; k < 8; ++k) bf[k] = (bhalf)0.f;
  if (lq == 0) {
    int s = (tile & 1) * 16 + l15;
    const float* st = &P.state[(size_t)(s0 + s) * 30];
    if (!sw) {
      int t = tile >> 1;
      f32x2 v = *(const f32x2*)(st + 2 * t);
      bf[0] = (bhalf)v[0]; bf[1] = (bhalf)v[1]; bf[2] = (bhalf)1.0f;
    } else {
      int ts = (tile - 14) >> 1;
      f32x2 v0 = *(const f32x2*)(st + 14 + 4 * ts);
      f32x2 v1 = *(const f32x2*)(st + 16 + 4 * ts);
      bf[0] = (bhalf)v0[0]; bf[1] = (bhalf)v0[1];
      bf[2] = (bhalf)v1[0]; bf[3] = (bhalf)v1[1];
      bf[4] = (bhalf)1.0f;
    }
  }
  const bhalf* Aq = sw ? P.A_qs : P.A_qp;
  const bhalf* Ax = sw ? P.A_xs : P.A_xp;
  const int row = tile * 16 + l15;
#pragma unroll
  for (int n = 0; n < 6; ++n) {
    f32x4 c = {0.f, 0.f, 0.f, 0.f};
    c = mfma16(*(const bhalf8*)&Aq[(n * 16 + l15) * 32 + lq * 8], bf, c);
    bhalf4 o;
#pragma unroll
    for (int j = 0; j < 4; ++j) o[j] = (bhalf)c[j];
    *(bhalf4*)&s_q[row * 104 + n * 16 + lq * 4] = o;
  }
  cx0 = f32x4{0.f, 0.f, 0.f, 0.f};
  cx1 = f32x4{0.f, 0.f, 0.f, 0.f};
  cx0 = mfma16(*(const bhalf8*)&Ax[l15 * 32 + lq * 8], bf, cx0);
  cx1 = mfma16(*(const bhalf8*)&Ax[(16 + l15) * 32 + lq * 8], bf, cx1);
}

// ---------------- attention: reg output, qkv stride 104, token stride 32 rows ----------------
template <int T>
DEV bhalf8 attn_head(const bhalf* qkv, int rowbase, int a, int s, int h) {
  const bhalf* base = &qkv[(rowbase + s) * 104 + h * 8];
  const int rstep = 32 * 104;
  bhalf8 kf[T];
#pragma unroll
  for (int b = 0; b < T; ++b) kf[b] = *(const bhalf8*)(base + b * rstep + 32);
  bhalf8 qv = *(const bhalf8*)(base + a * rstep);
  float q[8];
#pragma unroll
  for (int i = 0; i < 8; ++i) q[i] = (float)qv[i];
  float sc[T];
  float mx = -1e30f;
#pragma unroll
  for (int b = 0; b < T; ++b) {
    float d = 0.f;
#pragma unroll
    for (int i = 0; i < 8; ++i) d += q[i] * (float)kf[b][i];
    d *= 0.35355339059327378f;  // 1/sqrt(8)
    sc[b] = d;
    mx = fmaxf(mx, d);
  }
  bhalf8 vf[T];
#pragma unroll
  for (int b = 0; b < T; ++b) vf[b] = *(const bhalf8*)(base + b * rstep + 64);
  float sum = 0.f;
#pragma unroll
  for (int b = 0; b < T; ++b) { sc[b] = __expf(sc[b] - mx); sum += sc[b]; }
  float inv = 1.f / sum;
  float o[8] = {0.f, 0.f, 0.f, 0.f, 0.f, 0.f, 0.f, 0.f};
#pragma unroll
  for (int b = 0; b < T; ++b) {
    float w = sc[b] * inv;
#pragma unroll
    for (int i = 0; i < 8; ++i) o[i] += w * (float)vf[b][i];
  }
  bhalf8 ov;
#pragma unroll
  for (int i = 0; i < 8; ++i) ov[i] = (bhalf)o[i];
  return ov;
}

// ---------------- fused encoder tile-chain (X' C-init from registers) ----------------
template <int T>
DEV void enc_tile(const bhalf* s_q, bhalf* s_x, int tile, int l15, int lq,
                  f32x4 c0, f32x4 c1,
                  const bhalf* wo, const bhalf* wf1, const bhalf* wf2,
                  const float* g1, const float* b1, const float* f1b,
                  const float* f2b, const float* g2, const float* b2) {
  const int rowbase = (T == 7) ? 0 : 224;
  const int a = (T == 7) ? (tile >> 1) : ((tile - 14) >> 1);
  const int s = (tile & 1) * 16 + l15;
  bhalf8 ov = attn_head<T>(s_q, rowbase, a, s, lq);
  const int row = tile * 16 + l15;
  // o-proj; C-init = X' (f32, includes o_b) from registers
  c0 = mfma16(*(const bhalf8*)&wo[l15 * 32 + lq * 8], ov, c0);
  c1 = mfma16(*(const bhalf8*)&wo[(16 + l15) * 32 + lq * 8], ov, c1);
  // LN1 in-register (row spread over lanes {l15, +16, +32, +48})
  float sum = 0.f, ss = 0.f;
#pragma unroll
  for (int j = 0; j < 4; ++j) { sum += c0[j] + c1[j]; ss += c0[j] * c0[j] + c1[j] * c1[j]; }
  sum += __shfl_xor(sum, 16); sum += __shfl_xor(sum, 32);
  ss += __shfl_xor(ss, 16); ss += __shfl_xor(ss, 32);
  float mu = sum * 0.03125f;
  float rs = rsqrtf(ss * 0.03125f - mu * mu + 1e-5f);
  f32x4 gg0 = *(const f32x4*)&g1[lq * 4], gg1 = *(const f32x4*)&g1[16 + lq * 4];
  f32x4 hb0 = *(const f32x4*)&b1[lq * 4], hb1 = *(const f32x4*)&b1[16 + lq * 4];
  float xn[8];
#pragma unroll
  for (int j = 0; j < 4; ++j) {
    xn[j] = (c0[j] - mu) * rs * gg0[j] + hb0[j];
    xn[4 + j] = (c1[j] - mu) * rs * gg1[j] + hb1[j];
  }
  bhalf4 p0, p1;
#pragma unroll
  for (int j = 0; j < 4; ++j) { p0[j] = (bhalf)xn[j]; p1[j] = (bhalf)xn[4 + j]; }
  *(bhalf4*)&s_x[sxo(row, lq * 4)] = p0;
  *(bhalf4*)&s_x[sxo(row, 16 + lq * 4)] = p1;
  bhalf8 bfr = *(const bhalf8*)&s_x[sxo(row, lq * 8)];
  // FF1 + relu (bounce via s_x; residual xn stays in regs)
  c0 = f32x4{0.f, 0.f, 0.f, 0.f};
  c1 = f32x4{0.f, 0.f, 0.f, 0.f};
  c0 = mfma16(*(const bhalf8*)&wf1[l15 * 32 + lq * 8], bfr, c0);
  c1 = mfma16(*(const bhalf8*)&wf1[(16 + l15) * 32 + lq * 8], bfr, c1);
  f32x4 fb0 = *(const f32x4*)&f1b[lq * 4], fb1 = *(const f32x4*)&f1b[16 + lq * 4];
#pragma unroll
  for (int j = 0; j < 4; ++j) {
    p0[j] = (bhalf)fmaxf(c0[j] + fb0[j], 0.f);
    p1[j] = (bhalf)fmaxf(c1[j] + fb1[j], 0.f);
  }
  *(bhalf4*)&s_x[sxo(row, lq * 4)] = p0;
  *(bhalf4*)&s_x[sxo(row, 16 + lq * 4)] = p1;
  bfr = *(const bhalf8*)&s_x[sxo(row, lq * 8)];
  // FF2 with C-init = xn + f2b (residual + bias), then LN2 -> s_x
  f32x4 f20 = *(const f32x4*)&f2b[lq * 4], f21 = *(const f32x4*)&f2b[16 + lq * 4];
#pragma unroll
  for (int j = 0; j < 4; ++j) { c0[j] = xn[j] + f20[j]; c1[j] = xn[4 + j] + f21[j]; }
  c0 = mfma16(*(const bhalf8*)&wf2[l15 * 32 + lq * 8], bfr, c0);
  c1 = mfma16(*(const bhalf8*)&wf2[(16 + l15) * 32 + lq * 8], bfr, c1);
  sum = 0.f; ss = 0.f;
#pragma unroll
  for (int j = 0; j < 4; ++j) { sum += c0[j] + c1[j]; ss += c0[j] * c0[j] + c1[j] * c1[j]; }
  sum += __shfl_xor(sum, 16); sum += __shfl_xor(sum, 32);
  ss += __shfl_xor(ss, 16); ss += __shfl_xor(ss, 32);
  mu = sum * 0.03125f;
  rs = rsqrtf(ss * 0.03125f - mu * mu + 1e-5f);
  f32x4 g20 = *(const f32x4*)&g2[lq * 4], g21 = *(const f32x4*)&g2[16 + lq * 4];
  f32x4 b20 = *(const f32x4*)&b2[lq * 4], b21 = *(const f32x4*)&b2[16 + lq * 4];
#pragma unroll
  for (int j = 0; j < 4; ++j) {
    p0[j] = (bhalf)((c0[j] - mu) * rs * g20[j] + b20[j]);
    p1[j] = (bhalf)((c1[j] - mu) * rs * g21[j] + b21[j]);
  }
  *(bhalf4*)&s_x[sxo(row, lq * 4)] = p0;
  *(bhalf4*)&s_x[sxo(row, 16 + lq * 4)] = p1;
}

// ---------------- main fused kernel: 32 samples/block ----------------
__launch_bounds__(512, 4)
__global__ void aac_main(Ptrs P) {
  // 18432 + 59904 = 78336 B -> 2 blocks/CU
  __shared__ __align__(16) bhalf s_x[288 * 32];   // LN2 out + chain bounces (swizzled)
  __shared__ __align__(16) bhalf s_q[288 * 104];  // qkv; aliases xcat/h1/h2

  bhalf* xcat = s_q;                   // [32][408] elems 0..13055
  bhalf* h1 = s_q + 13056;             // [32][136]
  float* h2 = (float*)(s_q + 17408);   // [32][140] f32

  const int tid = threadIdx.x;
  const int wave = tid >> 6, lane = tid & 63;
  const int l15 = lane & 15, lq = lane >> 4;
  const int s0 = blockIdx.x * 32;

  // ---- phase 1: per-wave chain tiles; QKV -> LDS, X' -> regs ----
  f32x4 xA0, xA1, xB0, xB1, xC0, xC1;
  p1_tile(P, s_q, wave, s0, l15, lq, xA0, xA1);
  p1_tile(P, s_q, wave + 8, s0, l15, lq, xB0, xB1);
  if (wave < 2) p1_tile(P, s_q, 16 + wave, s0, l15, lq, xC0, xC1);
  __syncthreads();  // A

  // ---- fused encoder: 18 tile-chains, 2-3 independent chains per wave ----
  enc_tile<7>(s_q, s_x, wave, l15, lq, xA0, xA1,
              P.w_o, P.w_f1, P.w_f2, P.p_g1, P.p_b1, P.p_f1b, P.p_f2b, P.p_g2, P.p_b2);
  if (wave < 6) {
    enc_tile<7>(s_q, s_x, wave + 8, l15, lq, xB0, xB1,
                P.w_o, P.w_f1, P.w_f2, P.p_g1, P.p_b1, P.p_f1b, P.p_f2b, P.p_g2, P.p_b2);
  } else {
    enc_tile<2>(s_q, s_x, wave + 8, l15, lq, xB0, xB1,
                P.w_o2, P.w_f12, P.w_f22, P.s_g1, P.s_b1, P.s_f1b, P.s_f2b, P.s_g2, P.s_b2);
  }
  if (wave < 2) {
    enc_tile<2>(s_q, s_x, 16 + wave, l15, lq, xC0, xC1,
                P.w_o2, P.w_f12, P.w_f22, P.s_g1, P.s_b1, P.s_f1b, P.s_f2b, P.s_g2, P.s_b2);
  }
  __syncthreads();  // B

  // ---- out_gemm + st_emb -> xcat (48 jobs, 6/wave) ----
#pragma unroll
  for (int k = 0; k < 2; ++k) {  // power out
    int f = wave + 8 * k;
    int n = f >> 1, m = f & 1;
    f32x4 c = {0.f, 0.f, 0.f, 0.f};
#pragma unroll
    for (int t = 0; t < 7; ++t) {
      bhalf8 a = *(const bhalf8*)&P.w_out[(n * 16 + l15) * 224 + t * 32 + lq * 8];
      bhalf8 b = *(const bhalf8*)&s_x[sxo(t * 32 + m * 16 + l15, lq * 8)];
      c = mfma16(a, b, c);
    }
    int oc = n * 16 + lq * 4;
    f32x4 bias = *(const f32x4*)&P.p_out_b[oc];
    bhalf4 o;
#pragma unroll
    for (int j = 0; j < 4; ++j) o[j] = (bhalf)fmaxf(c[j] + bias[j], 0.f);
    *(bhalf4*)&xcat[(m * 16 + l15) * 408 + oc] = o;
  }
#pragma unroll
  for (int k = 0; k < 2; ++k) {  // sword out
    int g = wave + 8 * k;
    int n = g >> 1, m = g & 1;
    f32x4 c = {0.f, 0.f, 0.f, 0.f};
#pragma unroll
    for (int t = 0; t < 2; ++t) {
      bhalf8 a = *(const bhalf8*)&P.w_out2[(n * 16 + l15) * 64 + t * 32 + lq * 8];
      bhalf8 b = *(const bhalf8*)&s_x[sxo(224 + t * 32 + m * 16 + l15, lq * 8)];
      c = mfma16(a, b, c);
    }
    int oc = n * 16 + lq * 4;
    f32x4 bias = *(const f32x4*)&P.s_out_b[oc];
    bhalf4 o;
#pragma unroll
    for (int j = 0; j < 4; ++j) o[j] = (bhalf)fmaxf(c[j] + bias[j], 0.f);
    *(bhalf4*)&xcat[(m * 16 + l15) * 408 + 128 + oc] = o;
  }
#pragma unroll
  for (int k = 0; k < 2; ++k) {  // st_emb
    int g = wave + 8 * k;
    int n = g >> 1, m = g & 1;
    int s = m * 16 + l15;
    bhalf8 bf;
#pragma unroll
    for (int kk = 0; kk < 8; ++kk) bf[kk] = (bhalf)0.f;
    if (lq == 0) {
      const float* st = &P.state[(size_t)(s0 + s) * 30 + 22];
#pragma unroll
      for (int kk = 0; kk < 4; ++kk) {
        f32x2 v = *(const f32x2*)(st + 2 * kk);
        bf[2 * kk] = (bhalf)v[0];
        bf[2 * kk + 1] = (bhalf)v[1];
      }
    } else if (lq == 1) {
      bf[0] = (bhalf)1.0f;
    }
    bhalf8 a = *(const bhalf8*)&P.A_e[(n * 16 + l15) * 32 + lq * 8];
    f32x4 c = {0.f, 0.f, 0.f, 0.f};
    c = mfma16(a, bf, c);
    bhalf4 o;
#pragma unroll
    for (int j = 0; j < 4; ++j) o[j] = (bhalf)fmaxf(c[j], 0.f);
    *(bhalf4*)&xcat[s * 408 + 256 + n * 16 + lq * 4] = o;
  }
  __syncthreads();  // C

  // ---- d1: 2 independent jobs/wave (m=0,1; n=wave) -> h1 ----
#pragma unroll
  for (int m = 0; m < 2; ++m) {
    int n = wave;
    f32x4 c = {0.f, 0.f, 0.f, 0.f};
#pragma unroll
    for (int ks = 0; ks < 12; ++ks) {
      bhalf8 a = *(const bhalf8*)&P.w_d1[(n * 16 + l15) * 384 + ks * 32 + lq * 8];
      bhalf8 b = *(const bhalf8*)&xcat[(m * 16 + l15) * 408 + ks * 32 + lq * 8];
      c = mfma16(a, b, c);
    }
    int oc = n * 16 + lq * 4;
    f32x4 bias = *(const f32x4*)&P.d1_b[oc];
    bhalf4 o;
#pragma unroll
    for (int j = 0; j < 4; ++j) o[j] = (bhalf)fmaxf(c[j] + bias[j], 0.f);
    *(bhalf4*)&h1[(m * 16 + l15) * 136 + oc] = o;
  }
  __syncthreads();  // D

  // ---- d2: 2 independent jobs/wave -> h2 (f32) ----
#pragma unroll
  for (int m = 0; m < 2; ++m) {
    int n = wave;
    f32x4 c = {0.f, 0.f, 0.f, 0.f};
#pragma unroll
    for (int ks = 0; ks < 4; ++ks) {
      bhalf8 a = *(const bhalf8*)&P.w_d2[(n * 16 + l15) * 128 + ks * 32 + lq * 8];
      bhalf8 b = *(const bhalf8*)&h1[(m * 16 + l15) * 136 + ks * 32 + lq * 8];
      c = mfma16(a, b, c);
    }
    int oc = n * 16 + lq * 4;
    f32x4 bias = *(const f32x4*)&P.d2_b[oc];
    f32x4 o;
#pragma unroll
    for (int j = 0; j < 4; ++j) o[j] = fmaxf(c[j] + bias[j], 0.f);
    *(f32x4*)&h2[(m * 16 + l15) * 140 + oc] = o;
  }
  __syncthreads();  // E

  // ---- heads: 8 lanes/sample (32 samples x 8 outs = 256 threads) ----
  if (tid < 256) {
    int s = tid >> 3, o = tid & 7;
    const float* wrow = (o < 7) ? &P.pi_w[o * 128] : P.v_w;
    const float* hrow = &h2[s * 140];
    float acc = (o < 7) ? P.pi_b[o] : P.v_b[0];
#pragma unroll
    for (int k = 0; k < 32; ++k) {
      f32x4 wv = *(const f32x4*)&wrow[k * 4];
      f32x4 hv = *(const f32x4*)&hrow[k * 4];
#pragma unroll
      for (int j = 0; j < 4; ++j) acc += wv[j] * hv[j];
    }
    float xm = (o < 7) ? acc : -1e30f;
#pragma unroll
    for (int m = 1; m < 8; m <<= 1) xm = fmaxf(xm, __shfl_xor(xm, m));
    float e = (o < 7) ? __expf(acc - xm) : 0.f;
    float se = e;
#pragma unroll
    for (int m = 1; m < 8; m <<= 1) se += __shfl_xor(se, m);
    if (o < 7) P.out[(size_t)(s0 + s) * 7 + o] = e / se;
    else       P.out[917504 + s0 + s] = acc;  // 131072*7
  }
}

// ---------------- launch ----------------
extern "C" void kernel_launch(void* const* d_in, const int* in_sizes, int n_in,
                              void* d_out, int out_size, void* d_ws, size_t ws_size,
                              hipStream_t stream) {
  (void)in_sizes; (void)n_in; (void)out_size; (void)ws_size;
  const float* const* in = (const float* const*)d_in;
  bhalf* wbf = (bhalf*)d_ws;

  PrepArgs pa;
  const int srcIdx[10] = {5, 9, 11, 15, 21, 25, 27, 31, 35, 37};
  const int lens[10] = {1024, 1024, 1024, 28672, 1024, 1024, 1024, 8192, 49152, 16384};
  const int dsts[10] = {4096, 5120, 6144, 7168, 39936, 40960, 41984, 43008, 55296, 104448};
  for (int i = 0; i < 10; ++i) { pa.src[i] = in[srcIdx[i]]; pa.len[i] = lens[i]; pa.dstOff[i] = dsts[i]; }
  pa.dst = wbf;
  hipLaunchKernelGGL(prep_convert, dim3(424), dim3(256), 0, stream, pa);

  EffArgs ea;
  ea.p_qkv_w = in[3]; ea.p_in_w = in[1]; ea.p_in_b = in[2]; ea.p_qkv_b = in[4]; ea.p_o_b = in[6];
  ea.s_qkv_w = in[19]; ea.s_in_w = in[17]; ea.s_in_b = in[18]; ea.s_qkv_b = in[20]; ea.s_o_b = in[22];
  ea.e_w = in[33]; ea.e_b = in[34];
  ea.dst = wbf;
  hipLaunchKernelGGL(prep_eff, dim3(1), dim3(384), 0, stream, ea);

  Ptrs P;
  P.state = in[0];
  P.p_g1 = in[7];  P.p_b1 = in[8];  P.p_f1b = in[10]; P.p_f2b = in[12];
  P.p_g2 = in[13]; P.p_b2 = in[14]; P.p_out_b = in[16];
  P.s_g1 = in[23]; P.s_b1 = in[24]; P.s_f1b = in[26]; P.s_f2b = in[28];
  P.s_g2 = in[29]; P.s_b2 = in[30]; P.s_out_b = in[32];
  P.d1_b = in[36]; P.d2_b = in[38];
  P.pi_w = in[39]; P.pi_b = in[40]; P.v_w = in[41]; P.v_b = in[42];
  P.A_qp = wbf;          P.A_xp = wbf + 3072;   P.w_o = wbf + 4096;
  P.w_f1 = wbf + 5120;   P.w_f2 = wbf + 6144;   P.w_out = wbf + 7168;
  P.A_qs = wbf + 35840;  P.A_xs = wbf + 38912;  P.w_o2 = wbf + 39936;
  P.w_f12 = wbf + 40960; P.w_f22 = wbf + 41984; P.w_out2 = wbf + 43008;
  P.A_e = wbf + 51200;   P.w_d1 = wbf + 55296;  P.w_d2 = wbf + 104448;
  P.out = (float*)d_out;

  hipLaunchKernelGGL(aac_main, dim3(4096), dim3(512), 0, stream, P);  // 131072/32 blocks
}